// Round 6
// baseline (2327.429 us; speedup 1.0000x reference)
//
#include <hip/hip_runtime.h>
#include <hip/hip_bf16.h>
#include <cstdint>
#include <cstddef>

#define NNODES 50000
#define NEDGES 800000
#define HID 128
#define NRBF 32
#define NGRAPH 500
#define NB_SCAN 196   // ceil(50000/256)
#define EPB 64        // edges per block in edge_mfma
#define NEBLK (NEDGES / EPB)  // 12500

typedef __attribute__((ext_vector_type(8))) short short8;
typedef __attribute__((ext_vector_type(4))) float f32x4;

__device__ inline short f2bf(float x) {
  __hip_bfloat16 b = __float2bfloat16(x);
  return *reinterpret_cast<short*>(&b);
}

// ---------------- embed: h[n,c] = emb[x[n],c], float4 ----------------
__global__ void embed_kernel(const int* __restrict__ x, const float* __restrict__ emb,
                             float* __restrict__ h) {
  int i = blockIdx.x * blockDim.x + threadIdx.x;
  if (i >= NNODES * 32) return;
  int node = i >> 5, c4 = (i & 31) * 4;
  *(float4*)&h[(size_t)node * HID + c4] = *(const float4*)&emb[(size_t)x[node] * HID + c4];
}

// ------- edge-weight -> MFMA B-frag layout, bf16 -------
// WtB[((t*64)+lane)*8 + j] = W[k=quad*8+j][c=(t&7)*16 + (lane&15)], t<8: Wf, t>=8: Ws
__global__ void wedge_frags(const float* __restrict__ Wf, const float* __restrict__ Ws,
                            unsigned short* __restrict__ WtB) {
  int i = blockIdx.x * blockDim.x + threadIdx.x;  // 16*64*8 = 8192
  if (i >= 8192) return;
  int j = i & 7, lane = (i >> 3) & 63, t = i >> 9;
  int q = lane >> 4, n = lane & 15;
  int k = q * 8 + j, c = (t & 7) * 16 + n;
  const float* W = (t < 8) ? Wf : Ws;
  float v = W[(size_t)(256 + k) * HID + c];
  __hip_bfloat16 b = __float2bfloat16(v);
  WtB[i] = *reinterpret_cast<unsigned short*>(&b);
}

// ---------------- CSR build: histogram -> scan -> scatter ----------------
__global__ void deg_hist(const int* __restrict__ dst, int* __restrict__ deg) {
  int e = blockIdx.x * blockDim.x + threadIdx.x;
  if (e < NEDGES) atomicAdd(&deg[dst[e]], 1);
}

__global__ __launch_bounds__(256) void scan_block(const int* __restrict__ deg, int* __restrict__ bsum) {
  __shared__ int s[256];
  int i = blockIdx.x * 256 + threadIdx.x;
  s[threadIdx.x] = (i < NNODES) ? deg[i] : 0;
  __syncthreads();
  for (int off = 128; off > 0; off >>= 1) {
    if (threadIdx.x < off) s[threadIdx.x] += s[threadIdx.x + off];
    __syncthreads();
  }
  if (threadIdx.x == 0) bsum[blockIdx.x] = s[0];
}

__global__ void scan_top(const int* __restrict__ bsum, int* __restrict__ bpre,
                         int* __restrict__ rowptr) {
  if (threadIdx.x == 0) {
    int acc = 0;
    for (int b = 0; b < NB_SCAN; ++b) { bpre[b] = acc; acc += bsum[b]; }
    rowptr[NNODES] = acc;
  }
}

__global__ __launch_bounds__(256) void scan_final(const int* __restrict__ deg,
                                                  const int* __restrict__ bpre,
                                                  int* __restrict__ rowptr,
                                                  int* __restrict__ cursor) {
  __shared__ int s[256];
  int i = blockIdx.x * 256 + threadIdx.x;
  int v = (i < NNODES) ? deg[i] : 0;
  s[threadIdx.x] = v;
  __syncthreads();
  for (int off = 1; off < 256; off <<= 1) {
    int t = (threadIdx.x >= off) ? s[threadIdx.x - off] : 0;
    __syncthreads();
    s[threadIdx.x] += t;
    __syncthreads();
  }
  if (i < NNODES) {
    int ex = bpre[blockIdx.x] + s[threadIdx.x] - v;
    rowptr[i] = ex;
    cursor[i] = ex;
  }
}

// sorted arrays: se2[pos] = {src, dst}; eidS[pos] = original edge id
__global__ void scatter_edges(const int* __restrict__ src, const int* __restrict__ dst,
                              int* __restrict__ cursor, int2* __restrict__ se2,
                              int* __restrict__ eidS) {
  int e = blockIdx.x * blockDim.x + threadIdx.x;
  if (e < NEDGES) {
    int d = dst[e];
    int pos = atomicAdd(&cursor[d], 1);
    se2[pos] = make_int2(src[e], d);
    eidS[pos] = e;
  }
}

// ---------------- node GEMM: P = h @ [Wf_d|Wf_s|Ws_d|Ws_s] (unchanged, proven) ---------
__global__ __launch_bounds__(256) void node_gemm(
    const float* __restrict__ h, const float* __restrict__ Wf,
    const float* __restrict__ bf, const float* __restrict__ Ws,
    const float* __restrict__ bs, float* __restrict__ P, int N) {
  const int part = blockIdx.y;
  const int row0 = blockIdx.x * 128;
  const float* W = ((part < 2) ? Wf : Ws) + ((part & 1) ? (128 * HID) : 0);
  const float* bias = (part == 0) ? bf : ((part == 2) ? bs : nullptr);

  __shared__ __align__(16) float hsT[32][132];
  __shared__ __align__(16) float wsm[32][132];

  const int tc = threadIdx.x & 15;
  const int tr = threadIdx.x >> 4;

  float acc[8][8];
#pragma unroll
  for (int i = 0; i < 8; ++i)
#pragma unroll
    for (int j = 0; j < 8; ++j) acc[i][j] = 0.f;

  for (int kc = 0; kc < HID; kc += 32) {
#pragma unroll
    for (int j = 0; j < 4; ++j) {
      int i = threadIdx.x + 256 * j;
      int node = i >> 3;
      int kq = i & 7;
      int grow = row0 + node;
      if (grow >= N) grow = N - 1;
      const float4 v = *(const float4*)&h[(size_t)grow * HID + kc + kq * 4];
      hsT[kq * 4 + 0][node] = v.x;
      hsT[kq * 4 + 1][node] = v.y;
      hsT[kq * 4 + 2][node] = v.z;
      hsT[kq * 4 + 3][node] = v.w;
    }
#pragma unroll
    for (int j = 0; j < 4; ++j) {
      int i = threadIdx.x + 256 * j;
      int kk = i >> 5;
      int colq = i & 31;
      *(float4*)&wsm[kk][colq * 4] = *(const float4*)&W[(size_t)(kc + kk) * HID + colq * 4];
    }
    __syncthreads();
#pragma unroll
    for (int k = 0; k < 32; ++k) {
      float4 a0 = *(const float4*)&hsT[k][tr * 8];
      float4 a1 = *(const float4*)&hsT[k][tr * 8 + 4];
      float4 b0 = *(const float4*)&wsm[k][tc * 4];
      float4 b1 = *(const float4*)&wsm[k][tc * 4 + 64];
      float av[8] = {a0.x, a0.y, a0.z, a0.w, a1.x, a1.y, a1.z, a1.w};
      float bv[8] = {b0.x, b0.y, b0.z, b0.w, b1.x, b1.y, b1.z, b1.w};
#pragma unroll
      for (int i = 0; i < 8; ++i)
#pragma unroll
        for (int jj = 0; jj < 8; ++jj) acc[i][jj] += av[i] * bv[jj];
    }
    __syncthreads();
  }

  float badd[8];
#pragma unroll
  for (int half = 0; half < 2; ++half)
#pragma unroll
    for (int u = 0; u < 4; ++u)
      badd[half * 4 + u] = bias ? bias[half * 64 + tc * 4 + u] : 0.f;

  const int colBase = part * HID;
#pragma unroll
  for (int i = 0; i < 8; ++i) {
    int row = row0 + tr * 8 + i;
    if (row >= N) continue;
#pragma unroll
    for (int half = 0; half < 2; ++half) {
      float4 o;
      o.x = acc[i][half * 4 + 0] + badd[half * 4 + 0];
      o.y = acc[i][half * 4 + 1] + badd[half * 4 + 1];
      o.z = acc[i][half * 4 + 2] + badd[half * 4 + 2];
      o.w = acc[i][half * 4 + 3] + badd[half * 4 + 3];
      *(float4*)&P[(size_t)row * 512 + colBase + half * 64 + tc * 4] = o;
    }
  }
}

// ---------------- MFMA edge kernel ----------------
// Block: 256 threads = 4 waves, 64 sorted edges (wave w -> edges [b*64+w*16, +16)).
// af/as via mfma_f32_16x16x32_bf16: A = eattr strip [16e x 32k], B = Wedge frag tiles.
// C layout (m89): row(edge) = quad*4+reg, col = lane&15. Messages accumulated in a
// block LDS buffer keyed by local dst slot (in-block scan of sorted dsts); interior
// slots stored, boundary slots atomically added to agg.
__global__ __launch_bounds__(256) void edge_mfma(
    const float* __restrict__ P, const float* __restrict__ eattr,
    const unsigned short* __restrict__ WtB, const int2* __restrict__ se2,
    const int* __restrict__ eidS, float* __restrict__ agg) {
  __shared__ float accL[EPB * 130];
  __shared__ int sscan[EPB];
  __shared__ int slotArr[EPB];
  __shared__ int slot2dst[EPB];
  __shared__ int snd;

  const int tid = threadIdx.x;
  const int base = blockIdx.x * EPB;

  // zero accumulator
  for (int i = tid; i < EPB * 130; i += 256) accL[i] = 0.f;

  // in-block scan over sorted dsts -> slot per edge, dst per slot
  if (tid < EPB) {
    int d = se2[base + tid].y;
    int flag = 1;
    if (tid > 0) flag = (se2[base + tid - 1].y != d) ? 1 : 0;
    sscan[tid] = flag;
  }
  __syncthreads();
  for (int off = 1; off < EPB; off <<= 1) {
    int v = 0;
    if (tid < EPB) { v = sscan[tid]; if (tid >= off) v += sscan[tid - off]; }
    __syncthreads();
    if (tid < EPB) sscan[tid] = v;
    __syncthreads();
  }
  if (tid < EPB) {
    int d = se2[base + tid].y;
    int slot = sscan[tid] - 1;
    slotArr[tid] = slot;
    bool isfirst = (tid == 0) || (se2[base + tid - 1].y != d);
    if (isfirst) slot2dst[slot] = d;
    if (tid == EPB - 1) snd = sscan[EPB - 1];
  }
  __syncthreads();

  const int wv = tid >> 6;        // wave 0..3 -> strip
  const int lane = tid & 63;
  const int q = lane >> 4;        // quad
  const int n = lane & 15;
  const int sbase = base + wv * 16;

  // A-frag: eattr[strip edge n][k = q*8 + j], fp32 -> bf16
  const int eid = eidS[sbase + n];
  const float* ea = eattr + (size_t)eid * NRBF + q * 8;
  const float4 e0 = *(const float4*)ea;
  const float4 e1 = *(const float4*)(ea + 4);
  short8 afrag;
  afrag[0] = f2bf(e0.x); afrag[1] = f2bf(e0.y);
  afrag[2] = f2bf(e0.z); afrag[3] = f2bf(e0.w);
  afrag[4] = f2bf(e1.x); afrag[5] = f2bf(e1.y);
  afrag[6] = f2bf(e1.z); afrag[7] = f2bf(e1.w);

  // per-lane edge meta for the 4 C rows (edges q*4+reg of this strip)
  int srcr[4], dstr[4], slr[4];
#pragma unroll
  for (int r = 0; r < 4; ++r) {
    int li = wv * 16 + q * 4 + r;           // block-local edge index
    int2 sd = se2[base + li];
    srcr[r] = sd.x;
    dstr[r] = sd.y;
    slr[r] = slotArr[li];
  }

  const short8* WtB8 = (const short8*)WtB;
  const f32x4 zero4 = {0.f, 0.f, 0.f, 0.f};

#pragma unroll
  for (int t = 0; t < 8; ++t) {
    short8 bfr = WtB8[t * 64 + lane];         // Wf tile t (cols t*16..+15)
    short8 bsr = WtB8[(8 + t) * 64 + lane];   // Ws tile t
    f32x4 cf = __builtin_amdgcn_mfma_f32_16x16x32_bf16(afrag, bfr, zero4, 0, 0, 0);
    f32x4 cs = __builtin_amdgcn_mfma_f32_16x16x32_bf16(afrag, bsr, zero4, 0, 0, 0);
    const int c = t * 16 + n;
#pragma unroll
    for (int r = 0; r < 4; ++r) {
      const float* Pd = P + (size_t)dstr[r] * 512;
      const float* Ps = P + (size_t)srcr[r] * 512;
      float zf = cf[r] + Pd[c] + Ps[128 + c];          // bf folded into P part 0
      float zs = cs[r] + Pd[256 + c] + Ps[384 + c];    // bs folded into P part 2
      float sig = 1.f / (1.f + __expf(-zf));
      float sp = fmaxf(zs, 0.f) + __logf(1.f + __expf(-fabsf(zs)));
      atomicAdd(&accL[slr[r] * 130 + c], sig * sp);
    }
  }

  __syncthreads();

  // flush: interior slots exclusive to this block (sorted) -> plain store
  const int nd = snd;
  for (int i = tid; i < nd * 128; i += 256) {
    int sl = i >> 7, c = i & 127;
    float v = accL[sl * 130 + c];
    int d = slot2dst[sl];
    float* ap = agg + (size_t)d * HID + c;
    if (sl == 0 || sl == nd - 1) atomicAdd(ap, v);
    else *ap = v;
  }
}

// ---------------- h = relu(h + agg), float4 ----------------
__global__ void relu_add(float* __restrict__ h, const float* __restrict__ agg) {
  int i = blockIdx.x * blockDim.x + threadIdx.x;
  if (i >= NNODES * 32) return;
  float4 a = *(float4*)&h[(size_t)i * 4];
  float4 b = *(const float4*)&agg[(size_t)i * 4];
  float4 o;
  o.x = fmaxf(a.x + b.x, 0.f);
  o.y = fmaxf(a.y + b.y, 0.f);
  o.z = fmaxf(a.z + b.z, 0.f);
  o.w = fmaxf(a.w + b.w, 0.f);
  *(float4*)&h[(size_t)i * 4] = o;
}

// ---------------- pooling: segment sums + counts ----------------
__global__ void pool_kernel(const float* __restrict__ h, const int* __restrict__ batch,
                            float* __restrict__ sums, float* __restrict__ counts) {
  int i = blockIdx.x * blockDim.x + threadIdx.x;
  if (i >= NNODES * HID) return;
  int node = i >> 7, c = i & 127;
  int g = batch[node];
  atomicAdd(&sums[(size_t)g * HID + c], h[i]);
  if (c == 0) atomicAdd(&counts[g], 1.f);
}

// ---------------- out[g] = (sums[g]/max(cnt,1)) @ Wlin + blin ----------------
__global__ __launch_bounds__(128) void final_kernel(
    const float* __restrict__ sums, const float* __restrict__ counts,
    const float* __restrict__ Wlin, const float* __restrict__ blin,
    float* __restrict__ out) {
  int g = blockIdx.x;
  int c = threadIdx.x;
  __shared__ float pool[HID];
  float cnt = counts[g];
  cnt = cnt > 1.f ? cnt : 1.f;
  pool[c] = sums[(size_t)g * HID + c] / cnt;
  __syncthreads();
  float acc = blin[c];
#pragma unroll 8
  for (int k = 0; k < HID; ++k) acc = fmaf(pool[k], Wlin[k * HID + c], acc);
  out[(size_t)g * HID + c] = acc;
}

extern "C" void kernel_launch(void* const* d_in, const int* in_sizes, int n_in,
                              void* d_out, int out_size, void* d_ws, size_t ws_size,
                              hipStream_t stream) {
  const int* x = (const int*)d_in[0];
  const int* eidx = (const int*)d_in[1];
  const float* eattr = (const float*)d_in[2];
  const int* batch = (const int*)d_in[3];
  const float* emb = (const float*)d_in[4];
  const float* Wf[3] = {(const float*)d_in[5], (const float*)d_in[9], (const float*)d_in[13]};
  const float* bf[3] = {(const float*)d_in[6], (const float*)d_in[10], (const float*)d_in[14]};
  const float* Ws[3] = {(const float*)d_in[7], (const float*)d_in[11], (const float*)d_in[15]};
  const float* bs[3] = {(const float*)d_in[8], (const float*)d_in[12], (const float*)d_in[16]};
  const float* Wlin = (const float*)d_in[17];
  const float* blin = (const float*)d_in[18];
  const int* srcp = eidx;
  const int* dstp = eidx + NEDGES;

  float* wsf = (float*)d_ws;
  float* h = wsf;                                    // N*128
  float* P = h + (size_t)NNODES * HID;               // N*512
  float* agg = P + (size_t)NNODES * 512;             // N*128
  float* sums = agg + (size_t)NNODES * HID;          // 500*128
  float* counts = sums + (size_t)NGRAPH * HID;       // 500
  unsigned short* WtB = (unsigned short*)(counts + NGRAPH);  // 8192 ushort
  int2* se2 = (int2*)(WtB + 8192);                   // 800000 int2 (8B aligned)
  int* eidS = (int*)(se2 + NEDGES);                  // 800000
  int* deg = eidS + NEDGES;                          // 50000
  int* rowptr = deg + NNODES;                        // 50001
  int* cursor = rowptr + NNODES + 1;                 // 50000
  int* bsum = cursor + NNODES;                       // 196
  int* bpre = bsum + NB_SCAN;                        // 196

  // --- CSR build (edges layer-invariant: once per call) ---
  hipMemsetAsync(deg, 0, NNODES * sizeof(int), stream);
  deg_hist<<<(NEDGES + 255) / 256, 256, 0, stream>>>(dstp, deg);
  scan_block<<<NB_SCAN, 256, 0, stream>>>(deg, bsum);
  scan_top<<<1, 64, 0, stream>>>(bsum, bpre, rowptr);
  scan_final<<<NB_SCAN, 256, 0, stream>>>(deg, bpre, rowptr, cursor);
  scatter_edges<<<(NEDGES + 255) / 256, 256, 0, stream>>>(srcp, dstp, cursor, se2, eidS);

  embed_kernel<<<(NNODES * 32 + 255) / 256, 256, 0, stream>>>(x, emb, h);

  dim3 ggrid((NNODES + 127) / 128, 4);
  for (int l = 0; l < 3; ++l) {
    wedge_frags<<<32, 256, 0, stream>>>(Wf[l], Ws[l], WtB);
    node_gemm<<<ggrid, 256, 0, stream>>>(h, Wf[l], bf[l], Ws[l], bs[l], P, NNODES);
    hipMemsetAsync(agg, 0, (size_t)NNODES * HID * sizeof(float), stream);
    edge_mfma<<<NEBLK, 256, 0, stream>>>(P, eattr, WtB, se2, eidS, agg);
    relu_add<<<(NNODES * 32 + 255) / 256, 256, 0, stream>>>(h, agg);
  }

  hipMemsetAsync(sums, 0, (size_t)(NGRAPH * HID + NGRAPH) * sizeof(float), stream);
  pool_kernel<<<(NNODES * HID + 255) / 256, 256, 0, stream>>>(h, batch, sums, counts);
  final_kernel<<<NGRAPH, 128, 0, stream>>>(sums, counts, Wlin, blin, (float*)d_out);
}

// Round 7
// 1469.228 us; speedup vs baseline: 1.5841x; 1.5841x over previous
//
#include <hip/hip_runtime.h>
#include <hip/hip_bf16.h>
#include <cstdint>
#include <cstddef>

#define NNODES 50000
#define NEDGES 800000
#define HID 128
#define NRBF 32
#define NGRAPH 500
#define NB_SCAN 196   // ceil(50000/256)
#define EPB 64        // edges per block in edge_mfma
#define NEBLK (NEDGES / EPB)  // 12500
#define SROW 129      // LDS row stride (uints) for packed af/as: conflict-free

typedef __attribute__((ext_vector_type(8))) short short8;
typedef __attribute__((ext_vector_type(4))) float f32x4;

__device__ inline short f2bf(float x) {
  __hip_bfloat16 b = __float2bfloat16(x);
  return *reinterpret_cast<short*>(&b);
}

__device__ inline unsigned int packbf2(float a, float b) {
  __hip_bfloat16 ha = __float2bfloat16(a);
  __hip_bfloat16 hb = __float2bfloat16(b);
  unsigned short ua = *reinterpret_cast<unsigned short*>(&ha);
  unsigned short ub = *reinterpret_cast<unsigned short*>(&hb);
  return (unsigned int)ua | ((unsigned int)ub << 16);
}

// ---------------- embed: h[n,c] = emb[x[n],c], float4 ----------------
__global__ void embed_kernel(const int* __restrict__ x, const float* __restrict__ emb,
                             float* __restrict__ h) {
  int i = blockIdx.x * blockDim.x + threadIdx.x;
  if (i >= NNODES * 32) return;
  int node = i >> 5, c4 = (i & 31) * 4;
  *(float4*)&h[(size_t)node * HID + c4] = *(const float4*)&emb[(size_t)x[node] * HID + c4];
}

// ------- edge-weight -> MFMA B-frag layout, bf16 (layout verified in R6) -------
__global__ void wedge_frags(const float* __restrict__ Wf, const float* __restrict__ Ws,
                            unsigned short* __restrict__ WtB) {
  int i = blockIdx.x * blockDim.x + threadIdx.x;  // 16*64*8 = 8192
  if (i >= 8192) return;
  int j = i & 7, lane = (i >> 3) & 63, t = i >> 9;
  int q = lane >> 4, n = lane & 15;
  int k = q * 8 + j, c = (t & 7) * 16 + n;
  const float* W = (t < 8) ? Wf : Ws;
  float v = W[(size_t)(256 + k) * HID + c];
  __hip_bfloat16 b = __float2bfloat16(v);
  WtB[i] = *reinterpret_cast<unsigned short*>(&b);
}

// ---------------- CSR build: histogram -> scan -> scatter ----------------
__global__ void deg_hist(const int* __restrict__ dst, int* __restrict__ deg) {
  int e = blockIdx.x * blockDim.x + threadIdx.x;
  if (e < NEDGES) atomicAdd(&deg[dst[e]], 1);
}

__global__ __launch_bounds__(256) void scan_block(const int* __restrict__ deg, int* __restrict__ bsum) {
  __shared__ int s[256];
  int i = blockIdx.x * 256 + threadIdx.x;
  s[threadIdx.x] = (i < NNODES) ? deg[i] : 0;
  __syncthreads();
  for (int off = 128; off > 0; off >>= 1) {
    if (threadIdx.x < off) s[threadIdx.x] += s[threadIdx.x + off];
    __syncthreads();
  }
  if (threadIdx.x == 0) bsum[blockIdx.x] = s[0];
}

__global__ void scan_top(const int* __restrict__ bsum, int* __restrict__ bpre,
                         int* __restrict__ rowptr) {
  if (threadIdx.x == 0) {
    int acc = 0;
    for (int b = 0; b < NB_SCAN; ++b) { bpre[b] = acc; acc += bsum[b]; }
    rowptr[NNODES] = acc;
  }
}

__global__ __launch_bounds__(256) void scan_final(const int* __restrict__ deg,
                                                  const int* __restrict__ bpre,
                                                  int* __restrict__ rowptr,
                                                  int* __restrict__ cursor) {
  __shared__ int s[256];
  int i = blockIdx.x * 256 + threadIdx.x;
  int v = (i < NNODES) ? deg[i] : 0;
  s[threadIdx.x] = v;
  __syncthreads();
  for (int off = 1; off < 256; off <<= 1) {
    int t = (threadIdx.x >= off) ? s[threadIdx.x - off] : 0;
    __syncthreads();
    s[threadIdx.x] += t;
    __syncthreads();
  }
  if (i < NNODES) {
    int ex = bpre[blockIdx.x] + s[threadIdx.x] - v;
    rowptr[i] = ex;
    cursor[i] = ex;
  }
}

__global__ void scatter_edges(const int* __restrict__ src, const int* __restrict__ dst,
                              int* __restrict__ cursor, int2* __restrict__ se2,
                              int* __restrict__ eidS) {
  int e = blockIdx.x * blockDim.x + threadIdx.x;
  if (e < NEDGES) {
    int d = dst[e];
    int pos = atomicAdd(&cursor[d], 1);
    se2[pos] = make_int2(src[e], d);
    eidS[pos] = e;
  }
}

// ---------------- node GEMM: P = h @ [Wf_d|Wf_s|Ws_d|Ws_s] (unchanged, proven) ---------
__global__ __launch_bounds__(256) void node_gemm(
    const float* __restrict__ h, const float* __restrict__ Wf,
    const float* __restrict__ bf, const float* __restrict__ Ws,
    const float* __restrict__ bs, float* __restrict__ P, int N) {
  const int part = blockIdx.y;
  const int row0 = blockIdx.x * 128;
  const float* W = ((part < 2) ? Wf : Ws) + ((part & 1) ? (128 * HID) : 0);
  const float* bias = (part == 0) ? bf : ((part == 2) ? bs : nullptr);

  __shared__ __align__(16) float hsT[32][132];
  __shared__ __align__(16) float wsm[32][132];

  const int tc = threadIdx.x & 15;
  const int tr = threadIdx.x >> 4;

  float acc[8][8];
#pragma unroll
  for (int i = 0; i < 8; ++i)
#pragma unroll
    for (int j = 0; j < 8; ++j) acc[i][j] = 0.f;

  for (int kc = 0; kc < HID; kc += 32) {
#pragma unroll
    for (int j = 0; j < 4; ++j) {
      int i = threadIdx.x + 256 * j;
      int node = i >> 3;
      int kq = i & 7;
      int grow = row0 + node;
      if (grow >= N) grow = N - 1;
      const float4 v = *(const float4*)&h[(size_t)grow * HID + kc + kq * 4];
      hsT[kq * 4 + 0][node] = v.x;
      hsT[kq * 4 + 1][node] = v.y;
      hsT[kq * 4 + 2][node] = v.z;
      hsT[kq * 4 + 3][node] = v.w;
    }
#pragma unroll
    for (int j = 0; j < 4; ++j) {
      int i = threadIdx.x + 256 * j;
      int kk = i >> 5;
      int colq = i & 31;
      *(float4*)&wsm[kk][colq * 4] = *(const float4*)&W[(size_t)(kc + kk) * HID + colq * 4];
    }
    __syncthreads();
#pragma unroll
    for (int k = 0; k < 32; ++k) {
      float4 a0 = *(const float4*)&hsT[k][tr * 8];
      float4 a1 = *(const float4*)&hsT[k][tr * 8 + 4];
      float4 b0 = *(const float4*)&wsm[k][tc * 4];
      float4 b1 = *(const float4*)&wsm[k][tc * 4 + 64];
      float av[8] = {a0.x, a0.y, a0.z, a0.w, a1.x, a1.y, a1.z, a1.w};
      float bv[8] = {b0.x, b0.y, b0.z, b0.w, b1.x, b1.y, b1.z, b1.w};
#pragma unroll
      for (int i = 0; i < 8; ++i)
#pragma unroll
        for (int jj = 0; jj < 8; ++jj) acc[i][jj] += av[i] * bv[jj];
    }
    __syncthreads();
  }

  float badd[8];
#pragma unroll
  for (int half = 0; half < 2; ++half)
#pragma unroll
    for (int u = 0; u < 4; ++u)
      badd[half * 4 + u] = bias ? bias[half * 64 + tc * 4 + u] : 0.f;

  const int colBase = part * HID;
#pragma unroll
  for (int i = 0; i < 8; ++i) {
    int row = row0 + tr * 8 + i;
    if (row >= N) continue;
#pragma unroll
    for (int half = 0; half < 2; ++half) {
      float4 o;
      o.x = acc[i][half * 4 + 0] + badd[half * 4 + 0];
      o.y = acc[i][half * 4 + 1] + badd[half * 4 + 1];
      o.z = acc[i][half * 4 + 2] + badd[half * 4 + 2];
      o.w = acc[i][half * 4 + 3] + badd[half * 4 + 3];
      *(float4*)&P[(size_t)row * 512 + colBase + half * 64 + tc * 4] = o;
    }
  }
}

// ---------------- MFMA edge kernel, 3-phase ----------------
// Phase 1 (wave 0): ballot-scan the 64 sorted dsts -> group boundaries.
// Phase 2 (4 waves): MFMA eattr@Wedge for 64 edges x 256 outs; C-frags packed
//   bf16x2 {af,as} -> LDS (stride 129, conflict-free).
// Phase 3 (2 col-teams of 128): per dst-GROUP: Pd loaded once, per edge
//   1 ds_read + 2 src gathers + activations, register accumulate; interior
//   groups plain-store to agg, boundary groups (first/last) atomicAdd.
__global__ __launch_bounds__(256) void edge_mfma(
    const float* __restrict__ P, const float* __restrict__ eattr,
    const unsigned short* __restrict__ WtB, const int2* __restrict__ se2,
    const int* __restrict__ eidS, float* __restrict__ agg) {
  __shared__ unsigned int fsL[EPB * SROW];  // 33 KB packed {af,as}
  __shared__ int srcL[EPB];
  __shared__ int dstL[EPB];
  __shared__ int grpStart[EPB + 1];
  __shared__ int sndS;

  const int tid = threadIdx.x;
  const int base = blockIdx.x * EPB;
  const int lane = tid & 63;

  // ---- Phase 1: wave 0 ballot-scan ----
  if (tid < EPB) {
    int2 sd = se2[base + tid];
    srcL[tid] = sd.x;
    dstL[tid] = sd.y;
    int d = sd.y;
    int dprev = __shfl_up(d, 1);
    int flag = (lane == 0 || dprev != d) ? 1 : 0;
    unsigned long long mask = __ballot(flag);
    int slot = __popcll(mask & ((lane == 63) ? ~0ull : ((1ull << (lane + 1)) - 1))) - 1;
    if (flag) grpStart[slot] = lane;
    if (lane == 0) {
      int nd = __popcll(mask);
      sndS = nd;
      grpStart[nd] = EPB;
    }
  }

  // ---- Phase 2: MFMA ----
  const int wv = tid >> 6;
  const int q = lane >> 4;
  const int n = lane & 15;

  const int eid = eidS[base + wv * 16 + n];
  const float* ea = eattr + (size_t)eid * NRBF + q * 8;
  const float4 e0 = *(const float4*)ea;
  const float4 e1 = *(const float4*)(ea + 4);
  short8 afrag;
  afrag[0] = f2bf(e0.x); afrag[1] = f2bf(e0.y);
  afrag[2] = f2bf(e0.z); afrag[3] = f2bf(e0.w);
  afrag[4] = f2bf(e1.x); afrag[5] = f2bf(e1.y);
  afrag[6] = f2bf(e1.z); afrag[7] = f2bf(e1.w);

  const short8* WtB8 = (const short8*)WtB;
  const f32x4 zero4 = {0.f, 0.f, 0.f, 0.f};
  const int rowb = wv * 16 + q * 4;

#pragma unroll
  for (int t = 0; t < 8; ++t) {
    short8 bfr = WtB8[t * 64 + lane];
    short8 bsr = WtB8[(8 + t) * 64 + lane];
    f32x4 cf = __builtin_amdgcn_mfma_f32_16x16x32_bf16(afrag, bfr, zero4, 0, 0, 0);
    f32x4 cs = __builtin_amdgcn_mfma_f32_16x16x32_bf16(afrag, bsr, zero4, 0, 0, 0);
#pragma unroll
    for (int r = 0; r < 4; ++r) {
      fsL[(rowb + r) * SROW + t * 16 + n] = packbf2(cf[r], cs[r]);
    }
  }
  __syncthreads();

  // ---- Phase 3: per-group accumulation ----
  const int team = tid >> 7;
  const int c = tid & 127;
  const int nd = sndS;

  for (int g = team; g < nd; g += 2) {
    const int jb = grpStart[g];
    const int je = grpStart[g + 1];
    const int d = dstL[jb];
    const float pdf = P[(size_t)d * 512 + c];
    const float pds = P[(size_t)d * 512 + 256 + c];
    float acc = 0.f;
    for (int j = jb; j < je; ++j) {
      const int s = srcL[j];
      const unsigned int pk = fsL[j * SROW + c];
      const float af = __uint_as_float(pk << 16);
      const float as = __uint_as_float(pk & 0xffff0000u);
      const float psf = P[(size_t)s * 512 + 128 + c];
      const float pss = P[(size_t)s * 512 + 384 + c];
      float zf = pdf + psf + af;
      float zs = pds + pss + as;
      float sig = 1.f / (1.f + __expf(-zf));
      float sp = fmaxf(zs, 0.f) + __logf(1.f + __expf(-fabsf(zs)));
      acc = fmaf(sig, sp, acc);
    }
    float* ap = agg + (size_t)d * HID + c;
    if (g == 0 || g == nd - 1) atomicAdd(ap, acc);
    else *ap = acc;
  }
}

// ---------------- h = relu(h + agg), float4 ----------------
__global__ void relu_add(float* __restrict__ h, const float* __restrict__ agg) {
  int i = blockIdx.x * blockDim.x + threadIdx.x;
  if (i >= NNODES * 32) return;
  float4 a = *(float4*)&h[(size_t)i * 4];
  float4 b = *(const float4*)&agg[(size_t)i * 4];
  float4 o;
  o.x = fmaxf(a.x + b.x, 0.f);
  o.y = fmaxf(a.y + b.y, 0.f);
  o.z = fmaxf(a.z + b.z, 0.f);
  o.w = fmaxf(a.w + b.w, 0.f);
  *(float4*)&h[(size_t)i * 4] = o;
}

// ---------------- pooling: segment sums + counts ----------------
__global__ void pool_kernel(const float* __restrict__ h, const int* __restrict__ batch,
                            float* __restrict__ sums, float* __restrict__ counts) {
  int i = blockIdx.x * blockDim.x + threadIdx.x;
  if (i >= NNODES * HID) return;
  int node = i >> 7, c = i & 127;
  int g = batch[node];
  atomicAdd(&sums[(size_t)g * HID + c], h[i]);
  if (c == 0) atomicAdd(&counts[g], 1.f);
}

// ---------------- out[g] = (sums[g]/max(cnt,1)) @ Wlin + blin ----------------
__global__ __launch_bounds__(128) void final_kernel(
    const float* __restrict__ sums, const float* __restrict__ counts,
    const float* __restrict__ Wlin, const float* __restrict__ blin,
    float* __restrict__ out) {
  int g = blockIdx.x;
  int c = threadIdx.x;
  __shared__ float pool[HID];
  float cnt = counts[g];
  cnt = cnt > 1.f ? cnt : 1.f;
  pool[c] = sums[(size_t)g * HID + c] / cnt;
  __syncthreads();
  float acc = blin[c];
#pragma unroll 8
  for (int k = 0; k < HID; ++k) acc = fmaf(pool[k], Wlin[k * HID + c], acc);
  out[(size_t)g * HID + c] = acc;
}

extern "C" void kernel_launch(void* const* d_in, const int* in_sizes, int n_in,
                              void* d_out, int out_size, void* d_ws, size_t ws_size,
                              hipStream_t stream) {
  const int* x = (const int*)d_in[0];
  const int* eidx = (const int*)d_in[1];
  const float* eattr = (const float*)d_in[2];
  const int* batch = (const int*)d_in[3];
  const float* emb = (const float*)d_in[4];
  const float* Wf[3] = {(const float*)d_in[5], (const float*)d_in[9], (const float*)d_in[13]};
  const float* bf[3] = {(const float*)d_in[6], (const float*)d_in[10], (const float*)d_in[14]};
  const float* Ws[3] = {(const float*)d_in[7], (const float*)d_in[11], (const float*)d_in[15]};
  const float* bs[3] = {(const float*)d_in[8], (const float*)d_in[12], (const float*)d_in[16]};
  const float* Wlin = (const float*)d_in[17];
  const float* blin = (const float*)d_in[18];
  const int* srcp = eidx;
  const int* dstp = eidx + NEDGES;

  float* wsf = (float*)d_ws;
  float* h = wsf;                                    // N*128
  float* P = h + (size_t)NNODES * HID;               // N*512
  float* agg = P + (size_t)NNODES * 512;             // N*128
  float* sums = agg + (size_t)NNODES * HID;          // 500*128
  float* counts = sums + (size_t)NGRAPH * HID;       // 500
  unsigned short* WtB = (unsigned short*)(counts + NGRAPH);  // 8192 ushort
  int2* se2 = (int2*)(WtB + 8192);                   // 800000 int2
  int* eidS = (int*)(se2 + NEDGES);                  // 800000
  int* deg = eidS + NEDGES;                          // 50000
  int* rowptr = deg + NNODES;                        // 50001
  int* cursor = rowptr + NNODES + 1;                 // 50000
  int* bsum = cursor + NNODES;                       // 196
  int* bpre = bsum + NB_SCAN;                        // 196

  // --- CSR build (edges layer-invariant: once per call) ---
  hipMemsetAsync(deg, 0, NNODES * sizeof(int), stream);
  deg_hist<<<(NEDGES + 255) / 256, 256, 0, stream>>>(dstp, deg);
  scan_block<<<NB_SCAN, 256, 0, stream>>>(deg, bsum);
  scan_top<<<1, 64, 0, stream>>>(bsum, bpre, rowptr);
  scan_final<<<NB_SCAN, 256, 0, stream>>>(deg, bpre, rowptr, cursor);
  scatter_edges<<<(NEDGES + 255) / 256, 256, 0, stream>>>(srcp, dstp, cursor, se2, eidS);

  embed_kernel<<<(NNODES * 32 + 255) / 256, 256, 0, stream>>>(x, emb, h);

  dim3 ggrid((NNODES + 127) / 128, 4);
  for (int l = 0; l < 3; ++l) {
    wedge_frags<<<32, 256, 0, stream>>>(Wf[l], Ws[l], WtB);
    node_gemm<<<ggrid, 256, 0, stream>>>(h, Wf[l], bf[l], Ws[l], bs[l], P, NNODES);
    hipMemsetAsync(agg, 0, (size_t)NNODES * HID * sizeof(float), stream);
    edge_mfma<<<NEBLK, 256, 0, stream>>>(P, eattr, WtB, se2, eidS, agg);
    relu_add<<<(NNODES * 32 + 255) / 256, 256, 0, stream>>>(h, agg);
  }

  hipMemsetAsync(sums, 0, (size_t)(NGRAPH * HID + NGRAPH) * sizeof(float), stream);
  pool_kernel<<<(NNODES * HID + 255) / 256, 256, 0, stream>>>(h, batch, sums, counts);
  final_kernel<<<NGRAPH, 128, 0, stream>>>(sums, counts, Wlin, blin, (float*)d_out);
}

// Round 8
// 1405.945 us; speedup vs baseline: 1.6554x; 1.0450x over previous
//
#include <hip/hip_runtime.h>
#include <hip/hip_bf16.h>
#include <cstdint>
#include <cstddef>

#define NNODES 50000
#define NEDGES 800000
#define HID 128
#define NRBF 32
#define NGRAPH 500
#define NB_SCAN 196   // ceil(50000/256)
#define EPB 64        // edges per block in edge_mfma
#define NEBLK (NEDGES / EPB)  // 12500
#define SROW 130      // LDS row stride (uints): 4*130 % 32 == 8 -> exact 2-way (free)

typedef __attribute__((ext_vector_type(8))) short short8;
typedef __attribute__((ext_vector_type(4))) float f32x4;

__device__ inline short f2bf(float x) {
  __hip_bfloat16 b = __float2bfloat16(x);
  return *reinterpret_cast<short*>(&b);
}

__device__ inline unsigned int packbf2(float a, float b) {
  __hip_bfloat16 ha = __float2bfloat16(a);
  __hip_bfloat16 hb = __float2bfloat16(b);
  unsigned short ua = *reinterpret_cast<unsigned short*>(&ha);
  unsigned short ub = *reinterpret_cast<unsigned short*>(&hb);
  return (unsigned int)ua | ((unsigned int)ub << 16);
}

// ---------------- embed: h[n,c] = emb[x[n],c], float4 ----------------
__global__ void embed_kernel(const int* __restrict__ x, const float* __restrict__ emb,
                             float* __restrict__ h) {
  int i = blockIdx.x * blockDim.x + threadIdx.x;
  if (i >= NNODES * 32) return;
  int node = i >> 5, c4 = (i & 31) * 4;
  *(float4*)&h[(size_t)node * HID + c4] = *(const float4*)&emb[(size_t)x[node] * HID + c4];
}

// ------- edge-weight -> MFMA B-frag layout, bf16 (proven R6/R7) -------
__global__ void wedge_frags(const float* __restrict__ Wf, const float* __restrict__ Ws,
                            unsigned short* __restrict__ WtB) {
  int i = blockIdx.x * blockDim.x + threadIdx.x;  // 16*64*8 = 8192
  if (i >= 8192) return;
  int j = i & 7, lane = (i >> 3) & 63, t = i >> 9;
  int q = lane >> 4, n = lane & 15;
  int k = q * 8 + j, c = (t & 7) * 16 + n;
  const float* W = (t < 8) ? Wf : Ws;
  float v = W[(size_t)(256 + k) * HID + c];
  __hip_bfloat16 b = __float2bfloat16(v);
  WtB[i] = *reinterpret_cast<unsigned short*>(&b);
}

// ------- node-weight -> MFMA B-frag layout with interleaved column mapping -------
// Output col space (512): [0:256) dst-interleaved {Wf(c),Ws(c)} at {2c,2c+1} (k rows 0:128)
//                         [256:512) src-interleaved at {256+2c,256+2c+1}   (k rows 128:256)
// WnB[((tc*4+tk)*64+lane)*8+j] = Wbig[k=tk*32+q*8+j][cout=tc*16+n], bf16.
// biasv[cout]: bf/bs for dst half, 0 for src half.
__global__ void wnode_frags(const float* __restrict__ Wf, const float* __restrict__ Ws,
                            const float* __restrict__ bf, const float* __restrict__ bs,
                            unsigned short* __restrict__ WnB, float* __restrict__ biasv) {
  int i = blockIdx.x * blockDim.x + threadIdx.x;  // 32*4*64*8 = 65536
  if (i >= 65536) return;
  int j = i & 7;
  int lane = (i >> 3) & 63;
  int tk = (i >> 9) & 3;
  int tc = i >> 11;  // 0..31
  int q = lane >> 4, n = lane & 15;
  int k = tk * 32 + q * 8 + j;
  int cout = tc * 16 + n;
  int half = cout >> 8;
  int cc = cout & 255;
  int c = cc >> 1;
  int which = cc & 1;
  const float* W = which ? Ws : Wf;
  float v = W[(size_t)(half * 128 + k) * HID + c];
  __hip_bfloat16 b = __float2bfloat16(v);
  WnB[i] = *reinterpret_cast<unsigned short*>(&b);
  if (i < 512) {
    int h2 = i >> 8, cc2 = i & 255, c2 = cc2 >> 1, w2 = cc2 & 1;
    biasv[i] = h2 ? 0.f : (w2 ? bs[c2] : bf[c2]);
  }
}

// ---------------- CSR build: histogram -> scan -> scatter ----------------
__global__ void deg_hist(const int* __restrict__ dst, int* __restrict__ deg) {
  int e = blockIdx.x * blockDim.x + threadIdx.x;
  if (e < NEDGES) atomicAdd(&deg[dst[e]], 1);
}

__global__ __launch_bounds__(256) void scan_block(const int* __restrict__ deg, int* __restrict__ bsum) {
  __shared__ int s[256];
  int i = blockIdx.x * 256 + threadIdx.x;
  s[threadIdx.x] = (i < NNODES) ? deg[i] : 0;
  __syncthreads();
  for (int off = 128; off > 0; off >>= 1) {
    if (threadIdx.x < off) s[threadIdx.x] += s[threadIdx.x + off];
    __syncthreads();
  }
  if (threadIdx.x == 0) bsum[blockIdx.x] = s[0];
}

__global__ void scan_top(const int* __restrict__ bsum, int* __restrict__ bpre,
                         int* __restrict__ rowptr) {
  if (threadIdx.x == 0) {
    int acc = 0;
    for (int b = 0; b < NB_SCAN; ++b) { bpre[b] = acc; acc += bsum[b]; }
    rowptr[NNODES] = acc;
  }
}

__global__ __launch_bounds__(256) void scan_final(const int* __restrict__ deg,
                                                  const int* __restrict__ bpre,
                                                  int* __restrict__ rowptr,
                                                  int* __restrict__ cursor) {
  __shared__ int s[256];
  int i = blockIdx.x * 256 + threadIdx.x;
  int v = (i < NNODES) ? deg[i] : 0;
  s[threadIdx.x] = v;
  __syncthreads();
  for (int off = 1; off < 256; off <<= 1) {
    int t = (threadIdx.x >= off) ? s[threadIdx.x - off] : 0;
    __syncthreads();
    s[threadIdx.x] += t;
    __syncthreads();
  }
  if (i < NNODES) {
    int ex = bpre[blockIdx.x] + s[threadIdx.x] - v;
    rowptr[i] = ex;
    cursor[i] = ex;
  }
}

__global__ void scatter_edges(const int* __restrict__ src, const int* __restrict__ dst,
                              int* __restrict__ cursor, int2* __restrict__ se2,
                              int* __restrict__ eidS) {
  int e = blockIdx.x * blockDim.x + threadIdx.x;
  if (e < NEDGES) {
    int d = dst[e];
    int pos = atomicAdd(&cursor[d], 1);
    se2[pos] = make_int2(src[e], d);
    eidS[pos] = e;
  }
}

// ---------------- node MFMA GEMM: P[n][512 interleaved] = h @ Wbig + biasv ----------------
// Block 256 = 4 waves: wave (w>>1) -> 16-node group, (w&1) -> 256-col half.
// K=128 in 4 chained 16x16x32 MFMAs; 16 c-tiles per wave; acc 64 VGPRs.
__global__ __launch_bounds__(256) void node_mfma(
    const float* __restrict__ h, const unsigned short* __restrict__ WnB,
    const float* __restrict__ biasv, float* __restrict__ P, int N) {
  const int tid = threadIdx.x;
  const int wv = tid >> 6;
  const int lane = tid & 63;
  const int q = lane >> 4;
  const int n = lane & 15;
  const int nb = blockIdx.x * 32 + (wv >> 1) * 16;
  const int ctile0 = (wv & 1) * 16;

  // A-frags: A[m = n][k = q*8+j], 4 k-tiles
  int anode = nb + n;
  if (anode >= N) anode = N - 1;
  const float* hp = h + (size_t)anode * HID;
  short8 a[4];
#pragma unroll
  for (int kt = 0; kt < 4; ++kt) {
    const float4 e0 = *(const float4*)&hp[kt * 32 + q * 8];
    const float4 e1 = *(const float4*)&hp[kt * 32 + q * 8 + 4];
    a[kt][0] = f2bf(e0.x); a[kt][1] = f2bf(e0.y);
    a[kt][2] = f2bf(e0.z); a[kt][3] = f2bf(e0.w);
    a[kt][4] = f2bf(e1.x); a[kt][5] = f2bf(e1.y);
    a[kt][6] = f2bf(e1.z); a[kt][7] = f2bf(e1.w);
  }

  const short8* WnB8 = (const short8*)WnB;
  f32x4 acc[16];
#pragma unroll
  for (int tc = 0; tc < 16; ++tc) acc[tc] = (f32x4){0.f, 0.f, 0.f, 0.f};

#pragma unroll
  for (int tc = 0; tc < 16; ++tc) {
#pragma unroll
    for (int kt = 0; kt < 4; ++kt) {
      short8 b = WnB8[((size_t)((ctile0 + tc) * 4 + kt)) * 64 + lane];
      acc[tc] = __builtin_amdgcn_mfma_f32_16x16x32_bf16(a[kt], b, acc[tc], 0, 0, 0);
    }
  }

#pragma unroll
  for (int tc = 0; tc < 16; ++tc) {
    const int cout = (ctile0 + tc) * 16 + n;
    const float bv = biasv[cout];
#pragma unroll
    for (int r = 0; r < 4; ++r) {
      int nd = nb + q * 4 + r;
      if (nd < N) P[(size_t)nd * 512 + cout] = acc[tc][r] + bv;
    }
  }
}

// ---------------- MFMA edge kernel, 3-phase ----------------
// Phase 1 (wave 0): ballot-scan sorted dsts -> groups.
// Phase 2: MFMA eattr@Wedge, pack {af,as} bf16x2 -> LDS (stride 130, 2-way free).
// Phase 3 (2 col-teams): per dst group, Pd float2 once; per edge one saddr
//   dwordx2 src gather + LDS unpack + activations; register accumulate.
__global__ __launch_bounds__(256) void edge_mfma(
    const float* __restrict__ P, const float* __restrict__ eattr,
    const unsigned short* __restrict__ WtB, const int2* __restrict__ se2,
    const int* __restrict__ eidS, float* __restrict__ agg) {
  __shared__ unsigned int fsL[EPB * SROW];  // 33.3 KB packed {af,as}
  __shared__ int srcL[EPB];
  __shared__ int dstL[EPB];
  __shared__ int grpStart[EPB + 1];
  __shared__ int sndS;

  const int tid = threadIdx.x;
  const int base = blockIdx.x * EPB;
  const int lane = tid & 63;

  // ---- Phase 1: wave 0 ballot-scan ----
  if (tid < EPB) {
    int2 sd = se2[base + tid];
    srcL[tid] = sd.x;
    dstL[tid] = sd.y;
    int d = sd.y;
    int dprev = __shfl_up(d, 1);
    int flag = (lane == 0 || dprev != d) ? 1 : 0;
    unsigned long long mask = __ballot(flag);
    int slot = __popcll(mask & ((lane == 63) ? ~0ull : ((1ull << (lane + 1)) - 1))) - 1;
    if (flag) grpStart[slot] = lane;
    if (lane == 0) {
      int nd = __popcll(mask);
      sndS = nd;
      grpStart[nd] = EPB;
    }
  }

  // ---- Phase 2: MFMA ----
  const int wv = tid >> 6;
  const int q = lane >> 4;
  const int n = lane & 15;

  const int eid = eidS[base + wv * 16 + n];
  const float* ea = eattr + (size_t)eid * NRBF + q * 8;
  const float4 e0 = *(const float4*)ea;
  const float4 e1 = *(const float4*)(ea + 4);
  short8 afrag;
  afrag[0] = f2bf(e0.x); afrag[1] = f2bf(e0.y);
  afrag[2] = f2bf(e0.z); afrag[3] = f2bf(e0.w);
  afrag[4] = f2bf(e1.x); afrag[5] = f2bf(e1.y);
  afrag[6] = f2bf(e1.z); afrag[7] = f2bf(e1.w);

  const short8* WtB8 = (const short8*)WtB;
  const f32x4 zero4 = {0.f, 0.f, 0.f, 0.f};
  const int rowb = wv * 16 + q * 4;

#pragma unroll
  for (int t = 0; t < 8; ++t) {
    short8 bfr = WtB8[t * 64 + lane];
    short8 bsr = WtB8[(8 + t) * 64 + lane];
    f32x4 cf = __builtin_amdgcn_mfma_f32_16x16x32_bf16(afrag, bfr, zero4, 0, 0, 0);
    f32x4 cs = __builtin_amdgcn_mfma_f32_16x16x32_bf16(afrag, bsr, zero4, 0, 0, 0);
#pragma unroll
    for (int r = 0; r < 4; ++r) {
      fsL[(rowb + r) * SROW + t * 16 + n] = packbf2(cf[r], cs[r]);
    }
  }
  __syncthreads();

  // ---- Phase 3: per-group accumulation ----
  const int team = tid >> 7;
  const int c = tid & 127;
  const int nd = sndS;

  for (int g = team; g < nd; g += 2) {
    const int jb = grpStart[g];
    const int je = grpStart[g + 1];
    const int d = __builtin_amdgcn_readfirstlane(dstL[jb]);
    const float2 pd = *(const float2*)&P[(size_t)d * 512 + 2 * c];  // {zf_d, zs_d} incl bias
    float acc = 0.f;
    for (int j = jb; j < je; ++j) {
      const int s = __builtin_amdgcn_readfirstlane(srcL[j]);
      const float2 ps = *(const float2*)&P[(size_t)s * 512 + 256 + 2 * c];  // {psf, pss}
      const unsigned int pk = fsL[j * SROW + c];
      const float af = __uint_as_float(pk << 16);
      const float as = __uint_as_float(pk & 0xffff0000u);
      float zf = pd.x + ps.x + af;
      float zs = pd.y + ps.y + as;
      float sig = 1.f / (1.f + __expf(-zf));
      float sp = fmaxf(zs, 0.f) + __logf(1.f + __expf(-fabsf(zs)));
      acc = fmaf(sig, sp, acc);
    }
    float* ap = agg + (size_t)d * HID + c;
    if (g == 0 || g == nd - 1) atomicAdd(ap, acc);
    else *ap = acc;
  }
}

// ---------------- h = relu(h + agg), float4 ----------------
__global__ void relu_add(float* __restrict__ h, const float* __restrict__ agg) {
  int i = blockIdx.x * blockDim.x + threadIdx.x;
  if (i >= NNODES * 32) return;
  float4 a = *(float4*)&h[(size_t)i * 4];
  float4 b = *(const float4*)&agg[(size_t)i * 4];
  float4 o;
  o.x = fmaxf(a.x + b.x, 0.f);
  o.y = fmaxf(a.y + b.y, 0.f);
  o.z = fmaxf(a.z + b.z, 0.f);
  o.w = fmaxf(a.w + b.w, 0.f);
  *(float4*)&h[(size_t)i * 4] = o;
}

// ---------------- pooling: segment sums + counts ----------------
__global__ void pool_kernel(const float* __restrict__ h, const int* __restrict__ batch,
                            float* __restrict__ sums, float* __restrict__ counts) {
  int i = blockIdx.x * blockDim.x + threadIdx.x;
  if (i >= NNODES * HID) return;
  int node = i >> 7, c = i & 127;
  int g = batch[node];
  atomicAdd(&sums[(size_t)g * HID + c], h[i]);
  if (c == 0) atomicAdd(&counts[g], 1.f);
}

// ---------------- out[g] = (sums[g]/max(cnt,1)) @ Wlin + blin ----------------
__global__ __launch_bounds__(128) void final_kernel(
    const float* __restrict__ sums, const float* __restrict__ counts,
    const float* __restrict__ Wlin, const float* __restrict__ blin,
    float* __restrict__ out) {
  int g = blockIdx.x;
  int c = threadIdx.x;
  __shared__ float pool[HID];
  float cnt = counts[g];
  cnt = cnt > 1.f ? cnt : 1.f;
  pool[c] = sums[(size_t)g * HID + c] / cnt;
  __syncthreads();
  float acc = blin[c];
#pragma unroll 8
  for (int k = 0; k < HID; ++k) acc = fmaf(pool[k], Wlin[k * HID + c], acc);
  out[(size_t)g * HID + c] = acc;
}

extern "C" void kernel_launch(void* const* d_in, const int* in_sizes, int n_in,
                              void* d_out, int out_size, void* d_ws, size_t ws_size,
                              hipStream_t stream) {
  const int* x = (const int*)d_in[0];
  const int* eidx = (const int*)d_in[1];
  const float* eattr = (const float*)d_in[2];
  const int* batch = (const int*)d_in[3];
  const float* emb = (const float*)d_in[4];
  const float* Wf[3] = {(const float*)d_in[5], (const float*)d_in[9], (const float*)d_in[13]};
  const float* bf[3] = {(const float*)d_in[6], (const float*)d_in[10], (const float*)d_in[14]};
  const float* Ws[3] = {(const float*)d_in[7], (const float*)d_in[11], (const float*)d_in[15]};
  const float* bs[3] = {(const float*)d_in[8], (const float*)d_in[12], (const float*)d_in[16]};
  const float* Wlin = (const float*)d_in[17];
  const float* blin = (const float*)d_in[18];
  const int* srcp = eidx;
  const int* dstp = eidx + NEDGES;

  float* wsf = (float*)d_ws;
  float* h = wsf;                                    // N*128
  float* P = h + (size_t)NNODES * HID;               // N*512 (interleaved layout)
  float* agg = P + (size_t)NNODES * 512;             // N*128
  float* sums = agg + (size_t)NNODES * HID;          // 500*128
  float* counts = sums + (size_t)NGRAPH * HID;       // 500
  float* biasv = counts + NGRAPH;                    // 512
  unsigned short* WtB = (unsigned short*)(biasv + 512);   // 8192 ushort
  unsigned short* WnB = WtB + 8192;                  // 65536 ushort
  int2* se2 = (int2*)(WnB + 65536);                  // 800000 int2 (8B aligned)
  int* eidS = (int*)(se2 + NEDGES);                  // 800000
  int* deg = eidS + NEDGES;                          // 50000
  int* rowptr = deg + NNODES;                        // 50001
  int* cursor = rowptr + NNODES + 1;                 // 50000
  int* bsum = cursor + NNODES;                       // 196
  int* bpre = bsum + NB_SCAN;                        // 196

  // --- CSR build (edges layer-invariant: once per call) ---
  hipMemsetAsync(deg, 0, NNODES * sizeof(int), stream);
  deg_hist<<<(NEDGES + 255) / 256, 256, 0, stream>>>(dstp, deg);
  scan_block<<<NB_SCAN, 256, 0, stream>>>(deg, bsum);
  scan_top<<<1, 64, 0, stream>>>(bsum, bpre, rowptr);
  scan_final<<<NB_SCAN, 256, 0, stream>>>(deg, bpre, rowptr, cursor);
  scatter_edges<<<(NEDGES + 255) / 256, 256, 0, stream>>>(srcp, dstp, cursor, se2, eidS);

  embed_kernel<<<(NNODES * 32 + 255) / 256, 256, 0, stream>>>(x, emb, h);

  const int nblk_node = (NNODES + 31) / 32;  // 1563
  for (int l = 0; l < 3; ++l) {
    wedge_frags<<<32, 256, 0, stream>>>(Wf[l], Ws[l], WtB);
    wnode_frags<<<256, 256, 0, stream>>>(Wf[l], Ws[l], bf[l], bs[l], WnB, biasv);
    node_mfma<<<nblk_node, 256, 0, stream>>>(h, WnB, biasv, P, NNODES);
    hipMemsetAsync(agg, 0, (size_t)NNODES * HID * sizeof(float), stream);
    edge_mfma<<<NEBLK, 256, 0, stream>>>(P, eattr, WtB, se2, eidS, agg);
    relu_add<<<(NNODES * 32 + 255) / 256, 256, 0, stream>>>(h, agg);
  }

  hipMemsetAsync(sums, 0, (size_t)(NGRAPH * HID + NGRAPH) * sizeof(float), stream);
  pool_kernel<<<(NNODES * HID + 255) / 256, 256, 0, stream>>>(h, batch, sums, counts);
  final_kernel<<<NGRAPH, 128, 0, stream>>>(sums, counts, Wlin, blin, (float*)d_out);
}

// Round 9
// 1168.754 us; speedup vs baseline: 1.9914x; 1.2029x over previous
//
#include <hip/hip_runtime.h>
#include <hip/hip_bf16.h>
#include <cstdint>
#include <cstddef>

#define NNODES 50000
#define NEDGES 800000
#define HID 128
#define NRBF 32
#define NGRAPH 500
#define NB_SCAN 196   // ceil(50000/256)
#define EPB 64        // edges per block in edge_mfma
#define NEBLK (NEDGES / EPB)  // 12500
#define SROW 130      // LDS row stride (uints), keeps 8B alignment for uint2 reads

typedef __attribute__((ext_vector_type(8))) short short8;
typedef __attribute__((ext_vector_type(4))) float f32x4;

__device__ inline short f2bf(float x) {
  __hip_bfloat16 b = __float2bfloat16(x);
  return *reinterpret_cast<short*>(&b);
}

__device__ inline unsigned int packbf2(float a, float b) {
  __hip_bfloat16 ha = __float2bfloat16(a);
  __hip_bfloat16 hb = __float2bfloat16(b);
  unsigned short ua = *reinterpret_cast<unsigned short*>(&ha);
  unsigned short ub = *reinterpret_cast<unsigned short*>(&hb);
  return (unsigned int)ua | ((unsigned int)ub << 16);
}

// ---------------- embed: h[n,c] = emb[x[n],c], float4 ----------------
__global__ void embed_kernel(const int* __restrict__ x, const float* __restrict__ emb,
                             float* __restrict__ h) {
  int i = blockIdx.x * blockDim.x + threadIdx.x;
  if (i >= NNODES * 32) return;
  int node = i >> 5, c4 = (i & 31) * 4;
  *(float4*)&h[(size_t)node * HID + c4] = *(const float4*)&emb[(size_t)x[node] * HID + c4];
}

// ------- combined weight prep: edge-weight frags + node-weight frags + biasv -------
// i < 8192: WtB (edge weights rows 256:288, frag layout, proven R6/R7)
// else:     WnB (node weights, interleaved col mapping, proven R8) + biasv
__global__ void prep_weights(const float* __restrict__ Wf, const float* __restrict__ Ws,
                             const float* __restrict__ bf, const float* __restrict__ bs,
                             unsigned short* __restrict__ WtB,
                             unsigned short* __restrict__ WnB, float* __restrict__ biasv) {
  int i0 = blockIdx.x * blockDim.x + threadIdx.x;
  if (i0 < 8192) {
    int i = i0;
    int j = i & 7, lane = (i >> 3) & 63, t = i >> 9;
    int q = lane >> 4, n = lane & 15;
    int k = q * 8 + j, c = (t & 7) * 16 + n;
    const float* W = (t < 8) ? Wf : Ws;
    WtB[i] = (unsigned short)f2bf(W[(size_t)(256 + k) * HID + c]);
  } else if (i0 < 8192 + 65536) {
    int i = i0 - 8192;
    int j = i & 7;
    int lane = (i >> 3) & 63;
    int tk = (i >> 9) & 3;
    int tc = i >> 11;  // 0..31
    int q = lane >> 4, n = lane & 15;
    int k = tk * 32 + q * 8 + j;
    int cout = tc * 16 + n;
    int half = cout >> 8;
    int cc = cout & 255;
    int c = cc >> 1;
    int which = cc & 1;
    const float* W = which ? Ws : Wf;
    WnB[i] = (unsigned short)f2bf(W[(size_t)(half * 128 + k) * HID + c]);
    if (i < 512) {
      int h2 = i >> 8, cc2 = i & 255, c2 = cc2 >> 1, w2 = cc2 & 1;
      biasv[i] = h2 ? 0.f : (w2 ? bs[c2] : bf[c2]);
    }
  }
}

// ---------------- CSR build: histogram -> scan -> scatter ----------------
__global__ void deg_hist(const int* __restrict__ dst, int* __restrict__ deg) {
  int e = blockIdx.x * blockDim.x + threadIdx.x;
  if (e < NEDGES) atomicAdd(&deg[dst[e]], 1);
}

__global__ __launch_bounds__(256) void scan_block(const int* __restrict__ deg, int* __restrict__ bsum) {
  __shared__ int s[256];
  int i = blockIdx.x * 256 + threadIdx.x;
  s[threadIdx.x] = (i < NNODES) ? deg[i] : 0;
  __syncthreads();
  for (int off = 128; off > 0; off >>= 1) {
    if (threadIdx.x < off) s[threadIdx.x] += s[threadIdx.x + off];
    __syncthreads();
  }
  if (threadIdx.x == 0) bsum[blockIdx.x] = s[0];
}

__global__ void scan_top(const int* __restrict__ bsum, int* __restrict__ bpre,
                         int* __restrict__ rowptr) {
  if (threadIdx.x == 0) {
    int acc = 0;
    for (int b = 0; b < NB_SCAN; ++b) { bpre[b] = acc; acc += bsum[b]; }
    rowptr[NNODES] = acc;
  }
}

__global__ __launch_bounds__(256) void scan_final(const int* __restrict__ deg,
                                                  const int* __restrict__ bpre,
                                                  int* __restrict__ rowptr,
                                                  int* __restrict__ cursor) {
  __shared__ int s[256];
  int i = blockIdx.x * 256 + threadIdx.x;
  int v = (i < NNODES) ? deg[i] : 0;
  s[threadIdx.x] = v;
  __syncthreads();
  for (int off = 1; off < 256; off <<= 1) {
    int t = (threadIdx.x >= off) ? s[threadIdx.x - off] : 0;
    __syncthreads();
    s[threadIdx.x] += t;
    __syncthreads();
  }
  if (i < NNODES) {
    int ex = bpre[blockIdx.x] + s[threadIdx.x] - v;
    rowptr[i] = ex;
    cursor[i] = ex;
  }
}

__global__ void scatter_edges(const int* __restrict__ src, const int* __restrict__ dst,
                              int* __restrict__ cursor, int2* __restrict__ se2,
                              int* __restrict__ eidS) {
  int e = blockIdx.x * blockDim.x + threadIdx.x;
  if (e < NEDGES) {
    int d = dst[e];
    int pos = atomicAdd(&cursor[d], 1);
    se2[pos] = make_int2(src[e], d);
    eidS[pos] = e;
  }
}

// ---------------- node MFMA GEMM, fused relu-add ----------------
// If dorelu: h = relu(h + agg) computed in-place (each node row owned by one
// block; write gated to one wave), then P[n][512 interleaved] = h @ Wbig + biasv.
__global__ __launch_bounds__(256) void node_mfma(
    float* __restrict__ h, const float* __restrict__ agg,
    const unsigned short* __restrict__ WnB, const float* __restrict__ biasv,
    float* __restrict__ P, int dorelu, int N) {
  const int tid = threadIdx.x;
  const int wv = tid >> 6;
  const int lane = tid & 63;
  const int q = lane >> 4;
  const int n = lane & 15;
  const int nb = blockIdx.x * 32 + (wv >> 1) * 16;
  const int ctile0 = (wv & 1) * 16;

  const bool valid = (nb + n) < N;
  int anode = nb + n;
  if (anode >= N) anode = N - 1;
  float* hp = h + (size_t)anode * HID;
  const float* ap = agg + (size_t)anode * HID;

  short8 a[4];
#pragma unroll
  for (int kt = 0; kt < 4; ++kt) {
    float4 e0 = *(const float4*)&hp[kt * 32 + q * 8];
    float4 e1 = *(const float4*)&hp[kt * 32 + q * 8 + 4];
    if (dorelu) {
      const float4 g0 = *(const float4*)&ap[kt * 32 + q * 8];
      const float4 g1 = *(const float4*)&ap[kt * 32 + q * 8 + 4];
      e0.x = fmaxf(e0.x + g0.x, 0.f); e0.y = fmaxf(e0.y + g0.y, 0.f);
      e0.z = fmaxf(e0.z + g0.z, 0.f); e0.w = fmaxf(e0.w + g0.w, 0.f);
      e1.x = fmaxf(e1.x + g1.x, 0.f); e1.y = fmaxf(e1.y + g1.y, 0.f);
      e1.z = fmaxf(e1.z + g1.z, 0.f); e1.w = fmaxf(e1.w + g1.w, 0.f);
      if (valid && (wv & 1) == 0) {
        *(float4*)&hp[kt * 32 + q * 8] = e0;
        *(float4*)&hp[kt * 32 + q * 8 + 4] = e1;
      }
    }
    a[kt][0] = f2bf(e0.x); a[kt][1] = f2bf(e0.y);
    a[kt][2] = f2bf(e0.z); a[kt][3] = f2bf(e0.w);
    a[kt][4] = f2bf(e1.x); a[kt][5] = f2bf(e1.y);
    a[kt][6] = f2bf(e1.z); a[kt][7] = f2bf(e1.w);
  }

  const short8* WnB8 = (const short8*)WnB;
  f32x4 acc[16];
#pragma unroll
  for (int tc = 0; tc < 16; ++tc) acc[tc] = (f32x4){0.f, 0.f, 0.f, 0.f};

#pragma unroll
  for (int tc = 0; tc < 16; ++tc) {
#pragma unroll
    for (int kt = 0; kt < 4; ++kt) {
      short8 b = WnB8[((size_t)((ctile0 + tc) * 4 + kt)) * 64 + lane];
      acc[tc] = __builtin_amdgcn_mfma_f32_16x16x32_bf16(a[kt], b, acc[tc], 0, 0, 0);
    }
  }

#pragma unroll
  for (int tc = 0; tc < 16; ++tc) {
    const int cout = (ctile0 + tc) * 16 + n;
    const float bv = biasv[cout];
#pragma unroll
    for (int r = 0; r < 4; ++r) {
      int nd = nb + q * 4 + r;
      if (nd < N) P[(size_t)nd * 512 + cout] = acc[tc][r] + bv;
    }
  }
}

// ---------------- MFMA edge kernel, 3-phase ----------------
// Phase 1 (wave 0): ballot-scan sorted dsts -> groups.
// Phase 2 (4 waves): MFMA eattr@Wedge, pack {af,as} bf16x2 -> LDS.
// Phase 3 (4 single-wave teams): lane l covers channels {2l,2l+1}; per edge ONE
//   dwordx4 src gather + ONE ds_read_b64; per group one float4 Pd; register acc;
//   interior groups float2-store, boundary groups atomicAdd.
__global__ __launch_bounds__(256) void edge_mfma(
    const float* __restrict__ P, const float* __restrict__ eattr,
    const unsigned short* __restrict__ WtB, const int2* __restrict__ se2,
    const int* __restrict__ eidS, float* __restrict__ agg) {
  __shared__ unsigned int fsL[EPB * SROW];
  __shared__ int srcL[EPB];
  __shared__ int dstL[EPB];
  __shared__ int grpStart[EPB + 1];
  __shared__ int sndS;

  const int tid = threadIdx.x;
  const int base = blockIdx.x * EPB;
  const int lane = tid & 63;

  // ---- Phase 1: wave 0 ballot-scan ----
  if (tid < EPB) {
    int2 sd = se2[base + tid];
    srcL[tid] = sd.x;
    dstL[tid] = sd.y;
    int d = sd.y;
    int dprev = __shfl_up(d, 1);
    int flag = (lane == 0 || dprev != d) ? 1 : 0;
    unsigned long long mask = __ballot(flag);
    int slot = __popcll(mask & ((lane == 63) ? ~0ull : ((1ull << (lane + 1)) - 1))) - 1;
    if (flag) grpStart[slot] = lane;
    if (lane == 0) {
      int nd = __popcll(mask);
      sndS = nd;
      grpStart[nd] = EPB;
    }
  }

  // ---- Phase 2: MFMA ----
  const int wv = tid >> 6;
  const int q = lane >> 4;
  const int n = lane & 15;

  const int eid = eidS[base + wv * 16 + n];
  const float* ea = eattr + (size_t)eid * NRBF + q * 8;
  const float4 e0 = *(const float4*)ea;
  const float4 e1 = *(const float4*)(ea + 4);
  short8 afrag;
  afrag[0] = f2bf(e0.x); afrag[1] = f2bf(e0.y);
  afrag[2] = f2bf(e0.z); afrag[3] = f2bf(e0.w);
  afrag[4] = f2bf(e1.x); afrag[5] = f2bf(e1.y);
  afrag[6] = f2bf(e1.z); afrag[7] = f2bf(e1.w);

  const short8* WtB8 = (const short8*)WtB;
  const f32x4 zero4 = {0.f, 0.f, 0.f, 0.f};
  const int rowb = wv * 16 + q * 4;

#pragma unroll
  for (int t = 0; t < 8; ++t) {
    short8 bfr = WtB8[t * 64 + lane];
    short8 bsr = WtB8[(8 + t) * 64 + lane];
    f32x4 cf = __builtin_amdgcn_mfma_f32_16x16x32_bf16(afrag, bfr, zero4, 0, 0, 0);
    f32x4 cs = __builtin_amdgcn_mfma_f32_16x16x32_bf16(afrag, bsr, zero4, 0, 0, 0);
#pragma unroll
    for (int r = 0; r < 4; ++r) {
      fsL[(rowb + r) * SROW + t * 16 + n] = packbf2(cf[r], cs[r]);
    }
  }
  __syncthreads();

  // ---- Phase 3: per-group accumulation, 4 wave-teams ----
  const int nd = sndS;
  for (int g = wv; g < nd; g += 4) {
    const int jb = grpStart[g];
    const int je = grpStart[g + 1];
    const int d = __builtin_amdgcn_readfirstlane(dstL[jb]);
    const float4 pd = *(const float4*)&P[(size_t)d * 512 + 4 * lane];  // {f0,s0,f1,s1}
    float acc0 = 0.f, acc1 = 0.f;
    for (int j = jb; j < je; ++j) {
      const int s = __builtin_amdgcn_readfirstlane(srcL[j]);
      const float4 ps = *(const float4*)&P[(size_t)s * 512 + 256 + 4 * lane];
      const uint2 pk = *(const uint2*)&fsL[j * SROW + 2 * lane];
      const float af0 = __uint_as_float(pk.x << 16);
      const float as0 = __uint_as_float(pk.x & 0xffff0000u);
      const float af1 = __uint_as_float(pk.y << 16);
      const float as1 = __uint_as_float(pk.y & 0xffff0000u);
      float zf0 = pd.x + ps.x + af0;
      float zs0 = pd.y + ps.y + as0;
      float zf1 = pd.z + ps.z + af1;
      float zs1 = pd.w + ps.w + as1;
      float sig0 = __builtin_amdgcn_rcpf(1.f + __expf(-zf0));
      float sig1 = __builtin_amdgcn_rcpf(1.f + __expf(-zf1));
      float sp0 = fmaxf(zs0, 0.f) + __logf(1.f + __expf(-fabsf(zs0)));
      float sp1 = fmaxf(zs1, 0.f) + __logf(1.f + __expf(-fabsf(zs1)));
      acc0 = fmaf(sig0, sp0, acc0);
      acc1 = fmaf(sig1, sp1, acc1);
    }
    float* ap = agg + (size_t)d * HID + 2 * lane;
    if (g == 0 || g == nd - 1) {
      atomicAdd(ap, acc0);
      atomicAdd(ap + 1, acc1);
    } else {
      *(float2*)ap = make_float2(acc0, acc1);
    }
  }
}

// ---------------- pooling with fused final relu: segment sums + counts ----------------
__global__ void pool_kernel(const float* __restrict__ h, const float* __restrict__ agg,
                            const int* __restrict__ batch,
                            float* __restrict__ sums, float* __restrict__ counts) {
  int i = blockIdx.x * blockDim.x + threadIdx.x;
  if (i >= NNODES * HID) return;
  int node = i >> 7, c = i & 127;
  int g = batch[node];
  float v = fmaxf(h[i] + agg[i], 0.f);
  atomicAdd(&sums[(size_t)g * HID + c], v);
  if (c == 0) atomicAdd(&counts[g], 1.f);
}

// ---------------- out[g] = (sums[g]/max(cnt,1)) @ Wlin + blin ----------------
__global__ __launch_bounds__(128) void final_kernel(
    const float* __restrict__ sums, const float* __restrict__ counts,
    const float* __restrict__ Wlin, const float* __restrict__ blin,
    float* __restrict__ out) {
  int g = blockIdx.x;
  int c = threadIdx.x;
  __shared__ float pool[HID];
  float cnt = counts[g];
  cnt = cnt > 1.f ? cnt : 1.f;
  pool[c] = sums[(size_t)g * HID + c] / cnt;
  __syncthreads();
  float acc = blin[c];
#pragma unroll 8
  for (int k = 0; k < HID; ++k) acc = fmaf(pool[k], Wlin[k * HID + c], acc);
  out[(size_t)g * HID + c] = acc;
}

extern "C" void kernel_launch(void* const* d_in, const int* in_sizes, int n_in,
                              void* d_out, int out_size, void* d_ws, size_t ws_size,
                              hipStream_t stream) {
  const int* x = (const int*)d_in[0];
  const int* eidx = (const int*)d_in[1];
  const float* eattr = (const float*)d_in[2];
  const int* batch = (const int*)d_in[3];
  const float* emb = (const float*)d_in[4];
  const float* Wf[3] = {(const float*)d_in[5], (const float*)d_in[9], (const float*)d_in[13]};
  const float* bf[3] = {(const float*)d_in[6], (const float*)d_in[10], (const float*)d_in[14]};
  const float* Ws[3] = {(const float*)d_in[7], (const float*)d_in[11], (const float*)d_in[15]};
  const float* bs[3] = {(const float*)d_in[8], (const float*)d_in[12], (const float*)d_in[16]};
  const float* Wlin = (const float*)d_in[17];
  const float* blin = (const float*)d_in[18];
  const int* srcp = eidx;
  const int* dstp = eidx + NEDGES;

  float* wsf = (float*)d_ws;
  float* h = wsf;                                    // N*128
  float* P = h + (size_t)NNODES * HID;               // N*512 (interleaved layout)
  float* agg = P + (size_t)NNODES * 512;             // N*128
  float* sums = agg + (size_t)NNODES * HID;          // 500*128
  float* counts = sums + (size_t)NGRAPH * HID;       // 500
  float* biasv = counts + NGRAPH;                    // 512
  unsigned short* WtB = (unsigned short*)(biasv + 512);   // 8192 ushort
  unsigned short* WnB = WtB + 8192;                  // 65536 ushort
  int2* se2 = (int2*)(WnB + 65536);                  // 800000 int2 (8B aligned)
  int* eidS = (int*)(se2 + NEDGES);                  // 800000
  int* deg = eidS + NEDGES;                          // 50000
  int* rowptr = deg + NNODES;                        // 50001
  int* cursor = rowptr + NNODES + 1;                 // 50000
  int* bsum = cursor + NNODES;                       // 196
  int* bpre = bsum + NB_SCAN;                        // 196

  // --- CSR build (edges layer-invariant: once per call) ---
  hipMemsetAsync(deg, 0, NNODES * sizeof(int), stream);
  deg_hist<<<(NEDGES + 255) / 256, 256, 0, stream>>>(dstp, deg);
  scan_block<<<NB_SCAN, 256, 0, stream>>>(deg, bsum);
  scan_top<<<1, 64, 0, stream>>>(bsum, bpre, rowptr);
  scan_final<<<NB_SCAN, 256, 0, stream>>>(deg, bpre, rowptr, cursor);
  scatter_edges<<<(NEDGES + 255) / 256, 256, 0, stream>>>(srcp, dstp, cursor, se2, eidS);

  embed_kernel<<<(NNODES * 32 + 255) / 256, 256, 0, stream>>>(x, emb, h);

  const int nblk_node = (NNODES + 31) / 32;  // 1563
  for (int l = 0; l < 3; ++l) {
    prep_weights<<<288, 256, 0, stream>>>(Wf[l], Ws[l], bf[l], bs[l], WtB, WnB, biasv);
    node_mfma<<<nblk_node, 256, 0, stream>>>(h, agg, WnB, biasv, P, l > 0 ? 1 : 0, NNODES);
    hipMemsetAsync(agg, 0, (size_t)NNODES * HID * sizeof(float), stream);
    edge_mfma<<<NEBLK, 256, 0, stream>>>(P, eattr, WtB, se2, eidS, agg);
  }

  hipMemsetAsync(sums, 0, (size_t)(NGRAPH * HID + NGRAPH) * sizeof(float), stream);
  pool_kernel<<<(NNODES * HID + 255) / 256, 256, 0, stream>>>(h, agg, batch, sums, counts);
  final_kernel<<<NGRAPH, 128, 0, stream>>>(sums, counts, Wlin, blin, (float*)d_out);
}

// Round 11
// 1039.398 us; speedup vs baseline: 2.2392x; 1.1245x over previous
//
#include <hip/hip_runtime.h>
#include <hip/hip_bf16.h>
#include <hip/hip_fp16.h>
#include <cstdint>
#include <cstddef>

#define NNODES 50000
#define NEDGES 800000
#define HID 128
#define NRBF 32
#define NGRAPH 500
#define NB_SCAN 196   // ceil(50000/256)
#define EPB 64        // edges per block in edge_mfma
#define NEBLK (NEDGES / EPB)  // 12500
#define SROW 130      // LDS row stride (uints), 8B-aligned uint2 reads

typedef __attribute__((ext_vector_type(8))) short short8;
typedef __attribute__((ext_vector_type(4))) float f32x4;

__device__ inline short f2bf(float x) {
  __hip_bfloat16 b = __float2bfloat16(x);
  return *reinterpret_cast<short*>(&b);
}

__device__ inline unsigned int packbf2(float a, float b) {
  __hip_bfloat16 ha = __float2bfloat16(a);
  __hip_bfloat16 hb = __float2bfloat16(b);
  unsigned short ua = *reinterpret_cast<unsigned short*>(&ha);
  unsigned short ub = *reinterpret_cast<unsigned short*>(&hb);
  return (unsigned int)ua | ((unsigned int)ub << 16);
}

// fp16 pair pack (Psrc): bf16 was too coarse here (R10 absmax 12 — projections
// scale with |h| which grows monotonically; fp16 ulp is 8x finer, range safe).
__device__ inline unsigned int packh2(float a, float b) {
  __half2 h = __floats2half2_rn(a, b);
  return *reinterpret_cast<unsigned int*>(&h);
}

// ------- weight prep: edge-weight frags (WtB) + node-weight frags (WnB) + bias -------
// WnB col space: tiles 0..15 = dst half, cout=tc*16+n -> {Wf,Ws} interleaved {2c,2c+1},
//   k rows 0:128. tiles 16..31 = src half: tile 16+2g -> Wf(c=g*16+n), tile 17+2g ->
//   Ws(c), k rows 128:256 (f/s pair lands in SAME lane -> in-lane fp16 packing).
__global__ void prep_weights(const float* __restrict__ Wf, const float* __restrict__ Ws,
                             const float* __restrict__ bf, const float* __restrict__ bs,
                             unsigned short* __restrict__ WtB,
                             unsigned short* __restrict__ WnB, float* __restrict__ biasv) {
  int i0 = blockIdx.x * blockDim.x + threadIdx.x;
  if (i0 < 8192) {
    int i = i0;
    int j = i & 7, lane = (i >> 3) & 63, t = i >> 9;
    int q = lane >> 4, n = lane & 15;
    int k = q * 8 + j, c = (t & 7) * 16 + n;
    const float* W = (t < 8) ? Wf : Ws;
    WtB[i] = (unsigned short)f2bf(W[(size_t)(256 + k) * HID + c]);
  } else if (i0 < 8192 + 65536) {
    int i = i0 - 8192;
    int j = i & 7;
    int lane = (i >> 3) & 63;
    int tk = (i >> 9) & 3;
    int tc = i >> 11;  // 0..31
    int q = lane >> 4, n = lane & 15;
    int k = tk * 32 + q * 8 + j;
    float v;
    if (tc < 16) {  // dst half
      int cc = tc * 16 + n;
      int c = cc >> 1, which = cc & 1;
      const float* W = which ? Ws : Wf;
      v = W[(size_t)k * HID + c];
    } else {  // src half
      int g = (tc - 16) >> 1, which = (tc - 16) & 1;
      int c = g * 16 + n;
      const float* W = which ? Ws : Wf;
      v = W[(size_t)(128 + k) * HID + c];
    }
    WnB[i] = (unsigned short)f2bf(v);
    if (i < 256) {
      int c2 = i >> 1, w2 = i & 1;
      biasv[i] = w2 ? bs[c2] : bf[c2];
    }
  }
}

// ---------------- CSR build: histogram -> scan -> scatter ----------------
__global__ void deg_hist(const int* __restrict__ dst, int* __restrict__ deg) {
  int e = blockIdx.x * blockDim.x + threadIdx.x;
  if (e < NEDGES) atomicAdd(&deg[dst[e]], 1);
}

__global__ __launch_bounds__(256) void scan_block(const int* __restrict__ deg, int* __restrict__ bsum) {
  __shared__ int s[256];
  int i = blockIdx.x * 256 + threadIdx.x;
  s[threadIdx.x] = (i < NNODES) ? deg[i] : 0;
  __syncthreads();
  for (int off = 128; off > 0; off >>= 1) {
    if (threadIdx.x < off) s[threadIdx.x] += s[threadIdx.x + off];
    __syncthreads();
  }
  if (threadIdx.x == 0) bsum[blockIdx.x] = s[0];
}

__global__ __launch_bounds__(256) void scan_top(const int* __restrict__ bsum,
                                                int* __restrict__ bpre,
                                                int* __restrict__ rowptr) {
  __shared__ int s[256];
  int t = threadIdx.x;
  int v = (t < NB_SCAN) ? bsum[t] : 0;
  s[t] = v;
  __syncthreads();
  for (int off = 1; off < 256; off <<= 1) {
    int u = (t >= off) ? s[t - off] : 0;
    __syncthreads();
    s[t] += u;
    __syncthreads();
  }
  if (t < NB_SCAN) bpre[t] = s[t] - v;
  if (t == NB_SCAN - 1) rowptr[NNODES] = s[t];
}

__global__ __launch_bounds__(256) void scan_final(const int* __restrict__ deg,
                                                  const int* __restrict__ bpre,
                                                  int* __restrict__ rowptr,
                                                  int* __restrict__ cursor) {
  __shared__ int s[256];
  int i = blockIdx.x * 256 + threadIdx.x;
  int v = (i < NNODES) ? deg[i] : 0;
  s[threadIdx.x] = v;
  __syncthreads();
  for (int off = 1; off < 256; off <<= 1) {
    int t = (threadIdx.x >= off) ? s[threadIdx.x - off] : 0;
    __syncthreads();
    s[threadIdx.x] += t;
    __syncthreads();
  }
  if (i < NNODES) {
    int ex = bpre[blockIdx.x] + s[threadIdx.x] - v;
    rowptr[i] = ex;
    cursor[i] = ex;
  }
}

__global__ void scatter_edges(const int* __restrict__ src, const int* __restrict__ dst,
                              int* __restrict__ cursor, int2* __restrict__ se2,
                              int* __restrict__ eidS) {
  int e = blockIdx.x * blockDim.x + threadIdx.x;
  if (e < NEDGES) {
    int d = dst[e];
    int pos = atomicAdd(&cursor[d], 1);
    se2[pos] = make_int2(src[e], d);
    eidS[pos] = e;
  }
}

// ------- eattr -> sorted-order bf16 (phase-2 reads become coalesced) -------
__global__ void ea_pack(const float* __restrict__ eattr, const int* __restrict__ eidS,
                        unsigned short* __restrict__ eaB) {
  int i = blockIdx.x * blockDim.x + threadIdx.x;
  if (i >= NEDGES * 4) return;
  int pos = i >> 2, part = i & 3;
  int e = eidS[pos];
  const float4 v0 = *(const float4*)&eattr[(size_t)e * NRBF + part * 8];
  const float4 v1 = *(const float4*)&eattr[(size_t)e * NRBF + part * 8 + 4];
  short8 o;
  o[0] = f2bf(v0.x); o[1] = f2bf(v0.y); o[2] = f2bf(v0.z); o[3] = f2bf(v0.w);
  o[4] = f2bf(v1.x); o[5] = f2bf(v1.y); o[6] = f2bf(v1.z); o[7] = f2bf(v1.w);
  *(short8*)&eaB[(size_t)pos * 32 + part * 8] = o;
}

// ---------------- node MFMA GEMM, fused embed (mode 0) / relu-add (mode 1) --------
// Pdst[n][256] fp32 interleaved {f,s}; Psrc[n][128] uint packed fp16 {f,s}.
// mode 1: ALL loads complete before the in-place h store (__syncthreads between)
// -- closes the wave0-store vs wave1-load race latent in R8-R10.
__global__ __launch_bounds__(256) void node_mfma(
    const int* __restrict__ x, const float* __restrict__ emb,
    float* __restrict__ h, const float* __restrict__ agg,
    const unsigned short* __restrict__ WnB, const float* __restrict__ biasv,
    float* __restrict__ Pdst, unsigned int* __restrict__ Psrc, int mode, int N) {
  const int tid = threadIdx.x;
  const int wv = tid >> 6;
  const int lane = tid & 63;
  const int q = lane >> 4;
  const int n = lane & 15;
  const int nb = blockIdx.x * 32 + (wv >> 1) * 16;
  const int srcwave = wv & 1;
  const int ctile0 = srcwave * 16;

  const bool valid = (nb + n) < N;
  int anode = nb + n;
  if (anode >= N) anode = N - 1;
  float* hp = h + (size_t)anode * HID;

  short8 a[4];
  if (mode == 0) {
    const float* ep = emb + (size_t)x[anode] * HID;
#pragma unroll
    for (int kt = 0; kt < 4; ++kt) {
      const float4 e0 = *(const float4*)&ep[kt * 32 + q * 8];
      const float4 e1 = *(const float4*)&ep[kt * 32 + q * 8 + 4];
      if (valid && !srcwave) {  // h only written in mode 0 (no reader) -> no race
        *(float4*)&hp[kt * 32 + q * 8] = e0;
        *(float4*)&hp[kt * 32 + q * 8 + 4] = e1;
      }
      a[kt][0] = f2bf(e0.x); a[kt][1] = f2bf(e0.y);
      a[kt][2] = f2bf(e0.z); a[kt][3] = f2bf(e0.w);
      a[kt][4] = f2bf(e1.x); a[kt][5] = f2bf(e1.y);
      a[kt][6] = f2bf(e1.z); a[kt][7] = f2bf(e1.w);
    }
  } else {
    const float* ap = agg + (size_t)anode * HID;
    float4 ev[8];
#pragma unroll
    for (int kt = 0; kt < 4; ++kt) {
      float4 e0 = *(const float4*)&hp[kt * 32 + q * 8];
      float4 e1 = *(const float4*)&hp[kt * 32 + q * 8 + 4];
      const float4 g0 = *(const float4*)&ap[kt * 32 + q * 8];
      const float4 g1 = *(const float4*)&ap[kt * 32 + q * 8 + 4];
      e0.x = fmaxf(e0.x + g0.x, 0.f); e0.y = fmaxf(e0.y + g0.y, 0.f);
      e0.z = fmaxf(e0.z + g0.z, 0.f); e0.w = fmaxf(e0.w + g0.w, 0.f);
      e1.x = fmaxf(e1.x + g1.x, 0.f); e1.y = fmaxf(e1.y + g1.y, 0.f);
      e1.z = fmaxf(e1.z + g1.z, 0.f); e1.w = fmaxf(e1.w + g1.w, 0.f);
      ev[2 * kt] = e0;
      ev[2 * kt + 1] = e1;
      a[kt][0] = f2bf(e0.x); a[kt][1] = f2bf(e0.y);
      a[kt][2] = f2bf(e0.z); a[kt][3] = f2bf(e0.w);
      a[kt][4] = f2bf(e1.x); a[kt][5] = f2bf(e1.y);
      a[kt][6] = f2bf(e1.z); a[kt][7] = f2bf(e1.w);
    }
    __syncthreads();  // all waves' h/agg reads done before any in-place h write
    if (valid && !srcwave) {
#pragma unroll
      for (int kt = 0; kt < 4; ++kt) {
        *(float4*)&hp[kt * 32 + q * 8] = ev[2 * kt];
        *(float4*)&hp[kt * 32 + q * 8 + 4] = ev[2 * kt + 1];
      }
    }
  }

  const short8* WnB8 = (const short8*)WnB;
  f32x4 acc[16];
#pragma unroll
  for (int tc = 0; tc < 16; ++tc) acc[tc] = (f32x4){0.f, 0.f, 0.f, 0.f};

#pragma unroll
  for (int tc = 0; tc < 16; ++tc) {
#pragma unroll
    for (int kt = 0; kt < 4; ++kt) {
      short8 b = WnB8[((size_t)((ctile0 + tc) * 4 + kt)) * 64 + lane];
      acc[tc] = __builtin_amdgcn_mfma_f32_16x16x32_bf16(a[kt], b, acc[tc], 0, 0, 0);
    }
  }

  if (!srcwave) {
#pragma unroll
    for (int tc = 0; tc < 16; ++tc) {
      const int cout = tc * 16 + n;
      const float bv = biasv[cout];
#pragma unroll
      for (int r = 0; r < 4; ++r) {
        int nd = nb + q * 4 + r;
        if (nd < N) Pdst[(size_t)nd * 256 + cout] = acc[tc][r] + bv;
      }
    }
  } else {
#pragma unroll
    for (int g2 = 0; g2 < 8; ++g2) {
      const int c = g2 * 16 + n;
#pragma unroll
      for (int r = 0; r < 4; ++r) {
        int nd = nb + q * 4 + r;
        if (nd < N) Psrc[(size_t)nd * 128 + c] = packh2(acc[2 * g2][r], acc[2 * g2 + 1][r]);
      }
    }
  }
}

// ---------------- MFMA edge kernel, 3-phase ----------------
__global__ __launch_bounds__(256) void edge_mfma(
    const float* __restrict__ Pdst, const unsigned int* __restrict__ Psrc,
    const unsigned short* __restrict__ eaB, const unsigned short* __restrict__ WtB,
    const int2* __restrict__ se2, float* __restrict__ agg) {
  __shared__ unsigned int fsL[EPB * SROW];
  __shared__ int srcL[EPB];
  __shared__ int dstL[EPB];
  __shared__ int grpStart[EPB + 1];
  __shared__ int sndS;

  const int tid = threadIdx.x;
  const int base = blockIdx.x * EPB;
  const int lane = tid & 63;

  // ---- Phase 1: wave 0 ballot-scan of sorted dsts -> groups ----
  if (tid < EPB) {
    int2 sd = se2[base + tid];
    srcL[tid] = sd.x;
    dstL[tid] = sd.y;
    int d = sd.y;
    int dprev = __shfl_up(d, 1);
    int flag = (lane == 0 || dprev != d) ? 1 : 0;
    unsigned long long mask = __ballot(flag);
    int slot = __popcll(mask & ((lane == 63) ? ~0ull : ((1ull << (lane + 1)) - 1))) - 1;
    if (flag) grpStart[slot] = lane;
    if (lane == 0) {
      int nd = __popcll(mask);
      sndS = nd;
      grpStart[nd] = EPB;
    }
  }

  // ---- Phase 2: MFMA (A-frags from pre-packed sorted bf16 eattr, coalesced) ----
  const int wv = tid >> 6;
  const int q = lane >> 4;
  const int n = lane & 15;

  const short8 afrag = *(const short8*)&eaB[(size_t)(base + wv * 16 + n) * 32 + q * 8];

  const short8* WtB8 = (const short8*)WtB;
  const f32x4 zero4 = {0.f, 0.f, 0.f, 0.f};
  const int rowb = wv * 16 + q * 4;

#pragma unroll
  for (int t = 0; t < 8; ++t) {
    short8 bfr = WtB8[t * 64 + lane];
    short8 bsr = WtB8[(8 + t) * 64 + lane];
    f32x4 cf = __builtin_amdgcn_mfma_f32_16x16x32_bf16(afrag, bfr, zero4, 0, 0, 0);
    f32x4 cs = __builtin_amdgcn_mfma_f32_16x16x32_bf16(afrag, bsr, zero4, 0, 0, 0);
#pragma unroll
    for (int r = 0; r < 4; ++r) {
      fsL[(rowb + r) * SROW + t * 16 + n] = packbf2(cf[r], cs[r]);
    }
  }
  __syncthreads();

  // ---- Phase 3: per-group accumulation, 4 wave-teams, 2 channels/lane ----
  const int nd = sndS;
  for (int g = wv; g < nd; g += 4) {
    const int jb = grpStart[g];
    const int je = grpStart[g + 1];
    const int d = __builtin_amdgcn_readfirstlane(dstL[jb]);
    const float4 pd = *(const float4*)&Pdst[(size_t)d * 256 + 4 * lane];  // {f0,s0,f1,s1}
    float acc0 = 0.f, acc1 = 0.f;
    for (int j = jb; j < je; ++j) {
      const int s = __builtin_amdgcn_readfirstlane(srcL[j]);
      const uint2 psp = *(const uint2*)&Psrc[(size_t)s * 128 + 2 * lane];
      const float2 ps0 = __half22float2(*reinterpret_cast<const __half2*>(&psp.x));
      const float2 ps1 = __half22float2(*reinterpret_cast<const __half2*>(&psp.y));
      const uint2 pk = *(const uint2*)&fsL[j * SROW + 2 * lane];
      const float af0 = __uint_as_float(pk.x << 16);
      const float as0 = __uint_as_float(pk.x & 0xffff0000u);
      const float af1 = __uint_as_float(pk.y << 16);
      const float as1 = __uint_as_float(pk.y & 0xffff0000u);
      float zf0 = pd.x + ps0.x + af0;
      float zs0 = pd.y + ps0.y + as0;
      float zf1 = pd.z + ps1.x + af1;
      float zs1 = pd.w + ps1.y + as1;
      float sig0 = __builtin_amdgcn_rcpf(1.f + __expf(-zf0));
      float sig1 = __builtin_amdgcn_rcpf(1.f + __expf(-zf1));
      float sp0 = fmaxf(zs0, 0.f) + __logf(1.f + __expf(-fabsf(zs0)));
      float sp1 = fmaxf(zs1, 0.f) + __logf(1.f + __expf(-fabsf(zs1)));
      acc0 = fmaf(sig0, sp0, acc0);
      acc1 = fmaf(sig1, sp1, acc1);
    }
    float* ap = agg + (size_t)d * HID + 2 * lane;
    if (g == 0 || g == nd - 1) {
      atomicAdd(ap, acc0);
      atomicAdd(ap + 1, acc1);
    } else {
      *(float2*)ap = make_float2(acc0, acc1);
    }
  }
}

// ---------------- pooling: batch is SORTED -> run-detection, few atomics ----------------
__global__ __launch_bounds__(256) void pool_kernel(
    const float* __restrict__ h, const float* __restrict__ agg,
    const int* __restrict__ batch, float* __restrict__ sums, float* __restrict__ counts) {
  __shared__ int gidL[64];
  __shared__ int grpS[65];
  __shared__ int sndP;

  const int tid = threadIdx.x;
  const int lane = tid & 63;
  const int wv = tid >> 6;
  const int nb = blockIdx.x * 64;
  int nvalid = NNODES - nb;
  if (nvalid > 64) nvalid = 64;

  if (tid < 64) {
    int node = nb + tid;
    int g = batch[node < NNODES ? node : NNODES - 1];
    gidL[tid] = g;
    int gprev = __shfl_up(g, 1);
    int flag = (tid < nvalid && (tid == 0 || gprev != g)) ? 1 : 0;
    unsigned long long mask = __ballot(flag);
    int slot = __popcll(mask & ((lane == 63) ? ~0ull : ((1ull << (lane + 1)) - 1))) - 1;
    if (flag) grpS[slot] = tid;
    if (tid == 0) {
      int nd = __popcll(mask);
      sndP = nd;
      grpS[nd] = nvalid;
    }
  }
  __syncthreads();

  const int nd = sndP;
  for (int g = wv; g < nd; g += 4) {
    const int jb = grpS[g];
    const int je = grpS[g + 1];
    const int gid = __builtin_amdgcn_readfirstlane(gidL[jb]);
    float a0 = 0.f, a1 = 0.f;
    for (int j = jb; j < je; ++j) {
      const float2 hv = *(const float2*)&h[(size_t)(nb + j) * HID + 2 * lane];
      const float2 av = *(const float2*)&agg[(size_t)(nb + j) * HID + 2 * lane];
      a0 += fmaxf(hv.x + av.x, 0.f);
      a1 += fmaxf(hv.y + av.y, 0.f);
    }
    float* sp = sums + (size_t)gid * HID + 2 * lane;
    const bool bnd = (g == 0 || g == nd - 1);
    if (bnd) {
      atomicAdd(sp, a0);
      atomicAdd(sp + 1, a1);
    } else {
      *(float2*)sp = make_float2(a0, a1);
    }
    if (lane == 0) {
      if (bnd) atomicAdd(&counts[gid], (float)(je - jb));
      else counts[gid] = (float)(je - jb);
    }
  }
}

// ---------------- out[g] = (sums[g]/max(cnt,1)) @ Wlin + blin ----------------
__global__ __launch_bounds__(128) void final_kernel(
    const float* __restrict__ sums, const float* __restrict__ counts,
    const float* __restrict__ Wlin, const float* __restrict__ blin,
    float* __restrict__ out) {
  int g = blockIdx.x;
  int c = threadIdx.x;
  __shared__ float pool[HID];
  float cnt = counts[g];
  cnt = cnt > 1.f ? cnt : 1.f;
  pool[c] = sums[(size_t)g * HID + c] / cnt;
  __syncthreads();
  float acc = blin[c];
#pragma unroll 8
  for (int k = 0; k < HID; ++k) acc = fmaf(pool[k], Wlin[k * HID + c], acc);
  out[(size_t)g * HID + c] = acc;
}

extern "C" void kernel_launch(void* const* d_in, const int* in_sizes, int n_in,
                              void* d_out, int out_size, void* d_ws, size_t ws_size,
                              hipStream_t stream) {
  const int* x = (const int*)d_in[0];
  const int* eidx = (const int*)d_in[1];
  const float* eattr = (const float*)d_in[2];
  const int* batch = (const int*)d_in[3];
  const float* emb = (const float*)d_in[4];
  const float* Wf[3] = {(const float*)d_in[5], (const float*)d_in[9], (const float*)d_in[13]};
  const float* bf[3] = {(const float*)d_in[6], (const float*)d_in[10], (const float*)d_in[14]};
  const float* Ws[3] = {(const float*)d_in[7], (const float*)d_in[11], (const float*)d_in[15]};
  const float* bs[3] = {(const float*)d_in[8], (const float*)d_in[12], (const float*)d_in[16]};
  const float* Wlin = (const float*)d_in[17];
  const float* blin = (const float*)d_in[18];
  const int* srcp = eidx;
  const int* dstp = eidx + NEDGES;

  float* wsf = (float*)d_ws;
  float* h = wsf;                                    // N*128
  float* Pdst = h + (size_t)NNODES * HID;            // N*256 fp32 interleaved
  float* agg = Pdst + (size_t)NNODES * 256;          // N*128
  float* sums = agg + (size_t)NNODES * HID;          // 500*128
  float* counts = sums + (size_t)NGRAPH * HID;       // 500
  float* biasv = counts + NGRAPH;                    // 256
  unsigned int* Psrc = (unsigned int*)(biasv + 256); // N*128 uint packed fp16
  unsigned short* WtB = (unsigned short*)(Psrc + (size_t)NNODES * 128);  // 8192
  unsigned short* WnB = WtB + 8192;                  // 65536
  unsigned short* eaB = WnB + 65536;                 // NEDGES*32 bf16
  int2* se2 = (int2*)(eaB + (size_t)NEDGES * 32);    // 800000 int2
  int* eidS = (int*)(se2 + NEDGES);                  // 800000
  int* deg = eidS + NEDGES;                          // 50000
  int* cursor = deg + NNODES;                        // 50000
  int* bsum = cursor + NNODES;                       // 196
  int* bpre = bsum + NB_SCAN;                        // 196
  int* rowptr = bpre + NB_SCAN;                      // 50001

  // --- CSR build (edges layer-invariant: once per call) ---
  hipMemsetAsync(deg, 0, NNODES * sizeof(int), stream);
  deg_hist<<<(NEDGES + 255) / 256, 256, 0, stream>>>(dstp, deg);
  scan_block<<<NB_SCAN, 256, 0, stream>>>(deg, bsum);
  scan_top<<<1, 256, 0, stream>>>(bsum, bpre, rowptr);
  scan_final<<<NB_SCAN, 256, 0, stream>>>(deg, bpre, rowptr, cursor);
  scatter_edges<<<(NEDGES + 255) / 256, 256, 0, stream>>>(srcp, dstp, cursor, se2, eidS);
  ea_pack<<<(NEDGES * 4 + 255) / 256, 256, 0, stream>>>(eattr, eidS, eaB);

  const int nblk_node = (NNODES + 31) / 32;  // 1563
  for (int l = 0; l < 3; ++l) {
    prep_weights<<<288, 256, 0, stream>>>(Wf[l], Ws[l], bf[l], bs[l], WtB, WnB, biasv);
    node_mfma<<<nblk_node, 256, 0, stream>>>(x, emb, h, agg, WnB, biasv, Pdst, Psrc,
                                             l > 0 ? 1 : 0, NNODES);
    hipMemsetAsync(agg, 0, (size_t)NNODES * HID * sizeof(float), stream);
    edge_mfma<<<NEBLK, 256, 0, stream>>>(Pdst, Psrc, eaB, WtB, se2, agg);
  }

  hipMemsetAsync(sums, 0, (size_t)(NGRAPH * HID + NGRAPH) * sizeof(float), stream);
  pool_kernel<<<(NNODES + 63) / 64, 256, 0, stream>>>(h, agg, batch, sums, counts);
  final_kernel<<<NGRAPH, 128, 0, stream>>>(sums, counts, Wlin, blin, (float*)d_out);
}

// Round 12
// 978.561 us; speedup vs baseline: 2.3784x; 1.0622x over previous
//
#include <hip/hip_runtime.h>
#include <hip/hip_bf16.h>
#include <hip/hip_fp16.h>
#include <cstdint>
#include <cstddef>

#define NNODES 50000
#define NEDGES 800000
#define HID 128
#define NRBF 32
#define NGRAPH 500
#define NB_SCAN 196   // ceil(50000/256)
#define EPB 32        // edges per block in edge_mfma (R12: 64->32 for occupancy)
#define NEBLK (NEDGES / EPB)  // 25000
#define SROW 130      // LDS row stride (uints), 8B-aligned uint2 reads, 2-way banks (free)

typedef __attribute__((ext_vector_type(8))) short short8;
typedef __attribute__((ext_vector_type(4))) float f32x4;

__device__ inline short f2bf(float x) {
  __hip_bfloat16 b = __float2bfloat16(x);
  return *reinterpret_cast<short*>(&b);
}

__device__ inline unsigned int packbf2(float a, float b) {
  __hip_bfloat16 ha = __float2bfloat16(a);
  __hip_bfloat16 hb = __float2bfloat16(b);
  unsigned short ua = *reinterpret_cast<unsigned short*>(&ha);
  unsigned short ub = *reinterpret_cast<unsigned short*>(&hb);
  return (unsigned int)ua | ((unsigned int)ub << 16);
}

// fp16 pair pack (Psrc): bf16 too coarse (R10 absmax 12); fp16 ulp 8x finer, range safe.
__device__ inline unsigned int packh2(float a, float b) {
  __half2 h = __floats2half2_rn(a, b);
  return *reinterpret_cast<unsigned int*>(&h);
}

// ------- ALL-layer weight prep in one launch (grid.y = layer) -------
// WtB: edge-weight rows 256:288 in MFMA B-frag layout (proven R6+).
// WnB col space: tiles 0..15 dst half interleaved {Wf,Ws}; tiles 16..31 src half,
//   f/s pair in SAME lane (for in-lane fp16 pack). biasv: dst-half bias.
__global__ void prep_all(
    const float* __restrict__ Wf0, const float* __restrict__ Ws0,
    const float* __restrict__ bf0, const float* __restrict__ bs0,
    const float* __restrict__ Wf1, const float* __restrict__ Ws1,
    const float* __restrict__ bf1, const float* __restrict__ bs1,
    const float* __restrict__ Wf2, const float* __restrict__ Ws2,
    const float* __restrict__ bf2, const float* __restrict__ bs2,
    unsigned short* __restrict__ WtB3, unsigned short* __restrict__ WnB3,
    float* __restrict__ biasv3) {
  const int l = blockIdx.y;
  const float* Wf = (l == 0) ? Wf0 : ((l == 1) ? Wf1 : Wf2);
  const float* Ws = (l == 0) ? Ws0 : ((l == 1) ? Ws1 : Ws2);
  const float* bf = (l == 0) ? bf0 : ((l == 1) ? bf1 : bf2);
  const float* bs = (l == 0) ? bs0 : ((l == 1) ? bs1 : bs2);
  unsigned short* WtB = WtB3 + l * 8192;
  unsigned short* WnB = WnB3 + l * 65536;
  float* biasv = biasv3 + l * 256;

  int i0 = blockIdx.x * blockDim.x + threadIdx.x;
  if (i0 < 8192) {
    int i = i0;
    int j = i & 7, lane = (i >> 3) & 63, t = i >> 9;
    int q = lane >> 4, n = lane & 15;
    int k = q * 8 + j, c = (t & 7) * 16 + n;
    const float* W = (t < 8) ? Wf : Ws;
    WtB[i] = (unsigned short)f2bf(W[(size_t)(256 + k) * HID + c]);
  } else if (i0 < 8192 + 65536) {
    int i = i0 - 8192;
    int j = i & 7;
    int lane = (i >> 3) & 63;
    int tk = (i >> 9) & 3;
    int tc = i >> 11;  // 0..31
    int q = lane >> 4, n = lane & 15;
    int k = tk * 32 + q * 8 + j;
    float v;
    if (tc < 16) {
      int cc = tc * 16 + n;
      int c = cc >> 1, which = cc & 1;
      const float* W = which ? Ws : Wf;
      v = W[(size_t)k * HID + c];
    } else {
      int g = (tc - 16) >> 1, which = (tc - 16) & 1;
      int c = g * 16 + n;
      const float* W = which ? Ws : Wf;
      v = W[(size_t)(128 + k) * HID + c];
    }
    WnB[i] = (unsigned short)f2bf(v);
    if (i < 256) {
      int c2 = i >> 1, w2 = i & 1;
      biasv[i] = w2 ? bs[c2] : bf[c2];
    }
  }
}

// ---------------- CSR build: histogram -> scan -> scatter(+eattr pack) ----------------
__global__ void deg_hist(const int* __restrict__ dst, int* __restrict__ deg) {
  int e = blockIdx.x * blockDim.x + threadIdx.x;
  if (e < NEDGES) atomicAdd(&deg[dst[e]], 1);
}

__global__ __launch_bounds__(256) void scan_block(const int* __restrict__ deg, int* __restrict__ bsum) {
  __shared__ int s[256];
  int i = blockIdx.x * 256 + threadIdx.x;
  s[threadIdx.x] = (i < NNODES) ? deg[i] : 0;
  __syncthreads();
  for (int off = 128; off > 0; off >>= 1) {
    if (threadIdx.x < off) s[threadIdx.x] += s[threadIdx.x + off];
    __syncthreads();
  }
  if (threadIdx.x == 0) bsum[blockIdx.x] = s[0];
}

__global__ __launch_bounds__(256) void scan_top(const int* __restrict__ bsum,
                                                int* __restrict__ bpre) {
  __shared__ int s[256];
  int t = threadIdx.x;
  int v = (t < NB_SCAN) ? bsum[t] : 0;
  s[t] = v;
  __syncthreads();
  for (int off = 1; off < 256; off <<= 1) {
    int u = (t >= off) ? s[t - off] : 0;
    __syncthreads();
    s[t] += u;
    __syncthreads();
  }
  if (t < NB_SCAN) bpre[t] = s[t] - v;
}

__global__ __launch_bounds__(256) void scan_final(const int* __restrict__ deg,
                                                  const int* __restrict__ bpre,
                                                  int* __restrict__ cursor) {
  __shared__ int s[256];
  int i = blockIdx.x * 256 + threadIdx.x;
  int v = (i < NNODES) ? deg[i] : 0;
  s[threadIdx.x] = v;
  __syncthreads();
  for (int off = 1; off < 256; off <<= 1) {
    int t = (threadIdx.x >= off) ? s[threadIdx.x - off] : 0;
    __syncthreads();
    s[threadIdx.x] += t;
    __syncthreads();
  }
  if (i < NNODES) cursor[i] = bpre[blockIdx.x] + s[threadIdx.x] - v;  // exclusive
}

// scatter + fused eattr->bf16 pack in sorted order (kills ea_pack kernel + eidS)
__global__ void scatter_edges_pack(const int* __restrict__ src, const int* __restrict__ dst,
                                   const float* __restrict__ eattr, int* __restrict__ cursor,
                                   int2* __restrict__ se2, unsigned short* __restrict__ eaB) {
  int e = blockIdx.x * blockDim.x + threadIdx.x;
  if (e >= NEDGES) return;
  int d = dst[e];
  int pos = atomicAdd(&cursor[d], 1);
  se2[pos] = make_int2(src[e], d);
  const float* ep = eattr + (size_t)e * NRBF;
  unsigned short* op = eaB + (size_t)pos * NRBF;
#pragma unroll
  for (int part = 0; part < 4; ++part) {
    const float4 v0 = *(const float4*)&ep[part * 8];
    const float4 v1 = *(const float4*)&ep[part * 8 + 4];
    short8 o;
    o[0] = f2bf(v0.x); o[1] = f2bf(v0.y); o[2] = f2bf(v0.z); o[3] = f2bf(v0.w);
    o[4] = f2bf(v1.x); o[5] = f2bf(v1.y); o[6] = f2bf(v1.z); o[7] = f2bf(v1.w);
    *(short8*)&op[part * 8] = o;
  }
}

// ---------------- node MFMA GEMM, fused embed (mode 0) / relu-add (mode 1) --------
// Pdst[n][256] fp32 interleaved {f,s}; Psrc[n][128] uint packed fp16 {f,s}.
__global__ __launch_bounds__(256) void node_mfma(
    const int* __restrict__ x, const float* __restrict__ emb,
    float* __restrict__ h, const float* __restrict__ agg,
    const unsigned short* __restrict__ WnB, const float* __restrict__ biasv,
    float* __restrict__ Pdst, unsigned int* __restrict__ Psrc, int mode, int N) {
  const int tid = threadIdx.x;
  const int wv = tid >> 6;
  const int lane = tid & 63;
  const int q = lane >> 4;
  const int n = lane & 15;
  const int nb = blockIdx.x * 32 + (wv >> 1) * 16;
  const int srcwave = wv & 1;
  const int ctile0 = srcwave * 16;

  const bool valid = (nb + n) < N;
  int anode = nb + n;
  if (anode >= N) anode = N - 1;
  float* hp = h + (size_t)anode * HID;

  short8 a[4];
  if (mode == 0) {
    const float* ep = emb + (size_t)x[anode] * HID;
#pragma unroll
    for (int kt = 0; kt < 4; ++kt) {
      const float4 e0 = *(const float4*)&ep[kt * 32 + q * 8];
      const float4 e1 = *(const float4*)&ep[kt * 32 + q * 8 + 4];
      if (valid && !srcwave) {
        *(float4*)&hp[kt * 32 + q * 8] = e0;
        *(float4*)&hp[kt * 32 + q * 8 + 4] = e1;
      }
      a[kt][0] = f2bf(e0.x); a[kt][1] = f2bf(e0.y);
      a[kt][2] = f2bf(e0.z); a[kt][3] = f2bf(e0.w);
      a[kt][4] = f2bf(e1.x); a[kt][5] = f2bf(e1.y);
      a[kt][6] = f2bf(e1.z); a[kt][7] = f2bf(e1.w);
    }
  } else {
    const float* ap = agg + (size_t)anode * HID;
    float4 ev[8];
#pragma unroll
    for (int kt = 0; kt < 4; ++kt) {
      float4 e0 = *(const float4*)&hp[kt * 32 + q * 8];
      float4 e1 = *(const float4*)&hp[kt * 32 + q * 8 + 4];
      const float4 g0 = *(const float4*)&ap[kt * 32 + q * 8];
      const float4 g1 = *(const float4*)&ap[kt * 32 + q * 8 + 4];
      e0.x = fmaxf(e0.x + g0.x, 0.f); e0.y = fmaxf(e0.y + g0.y, 0.f);
      e0.z = fmaxf(e0.z + g0.z, 0.f); e0.w = fmaxf(e0.w + g0.w, 0.f);
      e1.x = fmaxf(e1.x + g1.x, 0.f); e1.y = fmaxf(e1.y + g1.y, 0.f);
      e1.z = fmaxf(e1.z + g1.z, 0.f); e1.w = fmaxf(e1.w + g1.w, 0.f);
      ev[2 * kt] = e0;
      ev[2 * kt + 1] = e1;
      a[kt][0] = f2bf(e0.x); a[kt][1] = f2bf(e0.y);
      a[kt][2] = f2bf(e0.z); a[kt][3] = f2bf(e0.w);
      a[kt][4] = f2bf(e1.x); a[kt][5] = f2bf(e1.y);
      a[kt][6] = f2bf(e1.z); a[kt][7] = f2bf(e1.w);
    }
    __syncthreads();  // all h/agg reads done before in-place h write (race fix R11)
    if (valid && !srcwave) {
#pragma unroll
      for (int kt = 0; kt < 4; ++kt) {
        *(float4*)&hp[kt * 32 + q * 8] = ev[2 * kt];
        *(float4*)&hp[kt * 32 + q * 8 + 4] = ev[2 * kt + 1];
      }
    }
  }

  const short8* WnB8 = (const short8*)WnB;
  f32x4 acc[16];
#pragma unroll
  for (int tc = 0; tc < 16; ++tc) acc[tc] = (f32x4){0.f, 0.f, 0.f, 0.f};

#pragma unroll
  for (int tc = 0; tc < 16; ++tc) {
#pragma unroll
    for (int kt = 0; kt < 4; ++kt) {
      short8 b = WnB8[((size_t)((ctile0 + tc) * 4 + kt)) * 64 + lane];
      acc[tc] = __builtin_amdgcn_mfma_f32_16x16x32_bf16(a[kt], b, acc[tc], 0, 0, 0);
    }
  }

  if (!srcwave) {
#pragma unroll
    for (int tc = 0; tc < 16; ++tc) {
      const int cout = tc * 16 + n;
      const float bv = biasv[cout];
#pragma unroll
      for (int r = 0; r < 4; ++r) {
        int nd = nb + q * 4 + r;
        if (nd < N) Pdst[(size_t)nd * 256 + cout] = acc[tc][r] + bv;
      }
    }
  } else {
#pragma unroll
    for (int g2 = 0; g2 < 8; ++g2) {
      const int c = g2 * 16 + n;
#pragma unroll
      for (int r = 0; r < 4; ++r) {
        int nd = nb + q * 4 + r;
        if (nd < N) Psrc[(size_t)nd * 128 + c] = packh2(acc[2 * g2][r], acc[2 * g2 + 1][r]);
      }
    }
  }
}

// ---------------- MFMA edge kernel, 3-phase, EPB=32 / 128 threads ----------------
// LDS 17 KB -> 9 blocks/CU (18 waves) vs R11's 34 KB / 4 blocks (16 waves, 34% occ).
__global__ __launch_bounds__(128) void edge_mfma(
    const float* __restrict__ Pdst, const unsigned int* __restrict__ Psrc,
    const unsigned short* __restrict__ eaB, const unsigned short* __restrict__ WtB,
    const int2* __restrict__ se2, float* __restrict__ agg) {
  __shared__ unsigned int fsL[EPB * SROW];
  __shared__ int srcL[EPB];
  __shared__ int dstL[EPB];
  __shared__ int grpStart[EPB + 1];
  __shared__ int sndS;

  const int tid = threadIdx.x;
  const int base = blockIdx.x * EPB;
  const int lane = tid & 63;

  // ---- Phase 1: wave-0 ballot-scan of sorted dsts -> groups ----
  if (tid < EPB) {
    int2 sd = se2[base + tid];
    srcL[tid] = sd.x;
    dstL[tid] = sd.y;
    int d = sd.y;
    int dprev = __shfl_up(d, 1);
    int flag = (tid == 0 || dprev != d) ? 1 : 0;
    unsigned long long mask = __ballot(flag);
    int slot = __popcll(mask & ((1ull << (lane + 1)) - 1)) - 1;
    if (flag) grpStart[slot] = tid;
    if (tid == 0) {
      int nd = __popcll(mask);
      sndS = nd;
      grpStart[nd] = EPB;
    }
  }

  // ---- Phase 2: MFMA (A-frags from pre-packed sorted bf16 eattr, coalesced) ----
  const int wv = tid >> 6;        // 0..1
  const int q = lane >> 4;
  const int n = lane & 15;

  const short8 afrag = *(const short8*)&eaB[(size_t)(base + wv * 16 + n) * 32 + q * 8];

  const short8* WtB8 = (const short8*)WtB;
  const f32x4 zero4 = {0.f, 0.f, 0.f, 0.f};
  const int rowb = wv * 16 + q * 4;

#pragma unroll
  for (int t = 0; t < 8; ++t) {
    short8 bfr = WtB8[t * 64 + lane];
    short8 bsr = WtB8[(8 + t) * 64 + lane];
    f32x4 cf = __builtin_amdgcn_mfma_f32_16x16x32_bf16(afrag, bfr, zero4, 0, 0, 0);
    f32x4 cs = __builtin_amdgcn_mfma_f32_16x16x32_bf16(afrag, bsr, zero4, 0, 0, 0);
#pragma unroll
    for (int r = 0; r < 4; ++r) {
      fsL[(rowb + r) * SROW + t * 16 + n] = packbf2(cf[r], cs[r]);
    }
  }
  __syncthreads();

  // ---- Phase 3: per-group accumulation, 2 wave-teams, 2 channels/lane ----
  const int nd = sndS;
  for (int g = wv; g < nd; g += 2) {
    const int jb = grpStart[g];
    const int je = grpStart[g + 1];
    const int d = __builtin_amdgcn_readfirstlane(dstL[jb]);
    const float4 pd = *(const float4*)&Pdst[(size_t)d * 256 + 4 * lane];  // {f0,s0,f1,s1}
    float acc0 = 0.f, acc1 = 0.f;
#pragma unroll 2
    for (int j = jb; j < je; ++j) {
      const int s = __builtin_amdgcn_readfirstlane(srcL[j]);
      const uint2 psp = *(const uint2*)&Psrc[(size_t)s * 128 + 2 * lane];
      const float2 ps0 = __half22float2(*reinterpret_cast<const __half2*>(&psp.x));
      const float2 ps1 = __half22float2(*reinterpret_cast<const __half2*>(&psp.y));
      const uint2 pk = *(const uint2*)&fsL[j * SROW + 2 * lane];
      const float af0 = __uint_as_float(pk.x << 16);
      const float as0 = __uint_as_float(pk.x & 0xffff0000u);
      const float af1 = __uint_as_float(pk.y << 16);
      const float as1 = __uint_as_float(pk.y & 0xffff0000u);
      float zf0 = pd.x + ps0.x + af0;
      float zs0 = pd.y + ps0.y + as0;
      float zf1 = pd.z + ps1.x + af1;
      float zs1 = pd.w + ps1.y + as1;
      float sig0 = __builtin_amdgcn_rcpf(1.f + __expf(-zf0));
      float sig1 = __builtin_amdgcn_rcpf(1.f + __expf(-zf1));
      float sp0 = fmaxf(zs0, 0.f) + __logf(1.f + __expf(-fabsf(zs0)));
      float sp1 = fmaxf(zs1, 0.f) + __logf(1.f + __expf(-fabsf(zs1)));
      acc0 = fmaf(sig0, sp0, acc0);
      acc1 = fmaf(sig1, sp1, acc1);
    }
    float* ap = agg + (size_t)d * HID + 2 * lane;
    if (g == 0 || g == nd - 1) {
      atomicAdd(ap, acc0);
      atomicAdd(ap + 1, acc1);
    } else {
      *(float2*)ap = make_float2(acc0, acc1);
    }
  }
}

// ---------------- pooling: batch is SORTED -> run-detection, few atomics ----------------
__global__ __launch_bounds__(256) void pool_kernel(
    const float* __restrict__ h, const float* __restrict__ agg,
    const int* __restrict__ batch, float* __restrict__ sums, float* __restrict__ counts) {
  __shared__ int gidL[64];
  __shared__ int grpS[65];
  __shared__ int sndP;

  const int tid = threadIdx.x;
  const int lane = tid & 63;
  const int wv = tid >> 6;
  const int nb = blockIdx.x * 64;
  int nvalid = NNODES - nb;
  if (nvalid > 64) nvalid = 64;

  if (tid < 64) {
    int node = nb + tid;
    int g = batch[node < NNODES ? node : NNODES - 1];
    gidL[tid] = g;
    int gprev = __shfl_up(g, 1);
    int flag = (tid < nvalid && (tid == 0 || gprev != g)) ? 1 : 0;
    unsigned long long mask = __ballot(flag);
    int slot = __popcll(mask & ((lane == 63) ? ~0ull : ((1ull << (lane + 1)) - 1))) - 1;
    if (flag) grpS[slot] = tid;
    if (tid == 0) {
      int nd = __popcll(mask);
      sndP = nd;
      grpS[nd] = nvalid;
    }
  }
  __syncthreads();

  const int nd = sndP;
  for (int g = wv; g < nd; g += 4) {
    const int jb = grpS[g];
    const int je = grpS[g + 1];
    const int gid = __builtin_amdgcn_readfirstlane(gidL[jb]);
    float a0 = 0.f, a1 = 0.f;
    for (int j = jb; j < je; ++j) {
      const float2 hv = *(const float2*)&h[(size_t)(nb + j) * HID + 2 * lane];
      const float2 av = *(const float2*)&agg[(size_t)(nb + j) * HID + 2 * lane];
      a0 += fmaxf(hv.x + av.x, 0.f);
      a1 += fmaxf(hv.y + av.y, 0.f);
    }
    float* sp = sums + (size_t)gid * HID + 2 * lane;
    const bool bnd = (g == 0 || g == nd - 1);
    if (bnd) {
      atomicAdd(sp, a0);
      atomicAdd(sp + 1, a1);
    } else {
      *(float2*)sp = make_float2(a0, a1);
    }
    if (lane == 0) {
      if (bnd) atomicAdd(&counts[gid], (float)(je - jb));
      else counts[gid] = (float)(je - jb);
    }
  }
}

// ---------------- out[g] = (sums[g]/max(cnt,1)) @ Wlin + blin ----------------
__global__ __launch_bounds__(128) void final_kernel(
    const float* __restrict__ sums, const float* __restrict__ counts,
    const float* __restrict__ Wlin, const float* __restrict__ blin,
    float* __restrict__ out) {
  int g = blockIdx.x;
  int c = threadIdx.x;
  __shared__ float pool[HID];
  float cnt = counts[g];
  cnt = cnt > 1.f ? cnt : 1.f;
  pool[c] = sums[(size_t)g * HID + c] / cnt;
  __syncthreads();
  float acc = blin[c];
#pragma unroll 8
  for (int k = 0; k < HID; ++k) acc = fmaf(pool[k], Wlin[k * HID + c], acc);
  out[(size_t)g * HID + c] = acc;
}

extern "C" void kernel_launch(void* const* d_in, const int* in_sizes, int n_in,
                              void* d_out, int out_size, void* d_ws, size_t ws_size,
                              hipStream_t stream) {
  const int* x = (const int*)d_in[0];
  const int* eidx = (const int*)d_in[1];
  const float* eattr = (const float*)d_in[2];
  const int* batch = (const int*)d_in[3];
  const float* emb = (const float*)d_in[4];
  const float* Wf[3] = {(const float*)d_in[5], (const float*)d_in[9], (const float*)d_in[13]};
  const float* bf[3] = {(const float*)d_in[6], (const float*)d_in[10], (const float*)d_in[14]};
  const float* Ws[3] = {(const float*)d_in[7], (const float*)d_in[11], (const float*)d_in[15]};
  const float* bs[3] = {(const float*)d_in[8], (const float*)d_in[12], (const float*)d_in[16]};
  const float* Wlin = (const float*)d_in[17];
  const float* blin = (const float*)d_in[18];
  const int* srcp = eidx;
  const int* dstp = eidx + NEDGES;

  float* wsf = (float*)d_ws;
  float* h = wsf;                                    // N*128
  float* Pdst = h + (size_t)NNODES * HID;            // N*256 fp32 interleaved
  float* agg = Pdst + (size_t)NNODES * 256;          // N*128
  float* sums = agg + (size_t)NNODES * HID;          // 500*128
  float* counts = sums + (size_t)NGRAPH * HID;       // 500
  float* biasv3 = counts + NGRAPH;                   // 3*256
  unsigned int* Psrc = (unsigned int*)(biasv3 + 768);  // N*128 uint packed fp16
  unsigned short* WtB3 = (unsigned short*)(Psrc + (size_t)NNODES * 128);  // 3*8192
  unsigned short* WnB3 = WtB3 + 3 * 8192;            // 3*65536
  unsigned short* eaB = WnB3 + 3 * 65536;            // NEDGES*32 bf16
  int2* se2 = (int2*)(eaB + (size_t)NEDGES * 32);    // 800000 int2
  int* deg = (int*)(se2 + NEDGES);                   // 50000
  int* cursor = deg + NNODES;                        // 50000
  int* bsum = cursor + NNODES;                       // 196
  int* bpre = bsum + NB_SCAN;                        // 196

  // --- weight prep (all 3 layers, one launch, independent of CSR) ---
  dim3 pgrid(288, 3);
  prep_all<<<pgrid, 256, 0, stream>>>(Wf[0], Ws[0], bf[0], bs[0],
                                      Wf[1], Ws[1], bf[1], bs[1],
                                      Wf[2], Ws[2], bf[2], bs[2],
                                      WtB3, WnB3, biasv3);

  // --- CSR build (edges layer-invariant: once per call) ---
  hipMemsetAsync(deg, 0, NNODES * sizeof(int), stream);
  deg_hist<<<(NEDGES + 255) / 256, 256, 0, stream>>>(dstp, deg);
  scan_block<<<NB_SCAN, 256, 0, stream>>>(deg, bsum);
  scan_top<<<1, 256, 0, stream>>>(bsum, bpre);
  scan_final<<<NB_SCAN, 256, 0, stream>>>(deg, bpre, cursor);
  scatter_edges_pack<<<(NEDGES + 255) / 256, 256, 0, stream>>>(srcp, dstp, eattr, cursor,
                                                               se2, eaB);

  const int nblk_node = (NNODES + 31) / 32;  // 1563
  for (int l = 0; l < 3; ++l) {
    node_mfma<<<nblk_node, 256, 0, stream>>>(x, emb, h, agg, WnB3 + l * 65536,
                                             biasv3 + l * 256, Pdst, Psrc,
                                             l > 0 ? 1 : 0, NNODES);
    hipMemsetAsync(agg, 0, (size_t)NNODES * HID * sizeof(float), stream);
    edge_mfma<<<NEBLK, 128, 0, stream>>>(Pdst, Psrc, eaB, WtB3 + l * 8192, se2, agg);
  }

  hipMemsetAsync(sums, 0, (size_t)(NGRAPH * HID + NGRAPH) * sizeof(float), stream);
  pool_kernel<<<(NNODES + 63) / 64, 256, 0, stream>>>(h, agg, batch, sums, counts);
  final_kernel<<<NGRAPH, 128, 0, stream>>>(sums, counts, Wlin, blin, (float*)d_out);
}

// Round 13
// 944.559 us; speedup vs baseline: 2.4640x; 1.0360x over previous
//
#include <hip/hip_runtime.h>
#include <hip/hip_bf16.h>
#include <hip/hip_fp16.h>
#include <cstdint>
#include <cstddef>

#define NNODES 50000
#define NEDGES 800000
#define HID 128
#define NRBF 32
#define NGRAPH 500
#define NB_SCAN 196   // ceil(50000/256)
#define EPB 32        // edges per block in edge_mfma
#define NEBLK (NEDGES / EPB)  // 25000
#define SROW 130      // LDS row stride (uints), 8B-aligned uint2 reads

typedef __attribute__((ext_vector_type(8))) short short8;
typedef __attribute__((ext_vector_type(4))) float f32x4;

__device__ inline short f2bf(float x) {
  __hip_bfloat16 b = __float2bfloat16(x);
  return *reinterpret_cast<short*>(&b);
}

__device__ inline unsigned int packbf2(float a, float b) {
  __hip_bfloat16 ha = __float2bfloat16(a);
  __hip_bfloat16 hb = __float2bfloat16(b);
  unsigned short ua = *reinterpret_cast<unsigned short*>(&ha);
  unsigned short ub = *reinterpret_cast<unsigned short*>(&hb);
  return (unsigned int)ua | ((unsigned int)ub << 16);
}

// fp16 pair pack (Psrc): bf16 too coarse (R10 absmax 12); fp16 ulp 8x finer, range safe.
__device__ inline unsigned int packh2(float a, float b) {
  __half2 h = __floats2half2_rn(a, b);
  return *reinterpret_cast<unsigned int*>(&h);
}

// ------- ALL-layer weight prep in one launch (grid.y = layer) -------
__global__ void prep_all(
    const float* __restrict__ Wf0, const float* __restrict__ Ws0,
    const float* __restrict__ bf0, const float* __restrict__ bs0,
    const float* __restrict__ Wf1, const float* __restrict__ Ws1,
    const float* __restrict__ bf1, const float* __restrict__ bs1,
    const float* __restrict__ Wf2, const float* __restrict__ Ws2,
    const float* __restrict__ bf2, const float* __restrict__ bs2,
    unsigned short* __restrict__ WtB3, unsigned short* __restrict__ WnB3,
    float* __restrict__ biasv3) {
  const int l = blockIdx.y;
  const float* Wf = (l == 0) ? Wf0 : ((l == 1) ? Wf1 : Wf2);
  const float* Ws = (l == 0) ? Ws0 : ((l == 1) ? Ws1 : Ws2);
  const float* bf = (l == 0) ? bf0 : ((l == 1) ? bf1 : bf2);
  const float* bs = (l == 0) ? bs0 : ((l == 1) ? bs1 : bs2);
  unsigned short* WtB = WtB3 + l * 8192;
  unsigned short* WnB = WnB3 + l * 65536;
  float* biasv = biasv3 + l * 256;

  int i0 = blockIdx.x * blockDim.x + threadIdx.x;
  if (i0 < 8192) {
    int i = i0;
    int j = i & 7, lane = (i >> 3) & 63, t = i >> 9;
    int q = lane >> 4, n = lane & 15;
    int k = q * 8 + j, c = (t & 7) * 16 + n;
    const float* W = (t < 8) ? Wf : Ws;
    WtB[i] = (unsigned short)f2bf(W[(size_t)(256 + k) * HID + c]);
  } else if (i0 < 8192 + 65536) {
    int i = i0 - 8192;
    int j = i & 7;
    int lane = (i >> 3) & 63;
    int tk = (i >> 9) & 3;
    int tc = i >> 11;  // 0..31
    int q = lane >> 4, n = lane & 15;
    int k = tk * 32 + q * 8 + j;
    float v;
    if (tc < 16) {
      int cc = tc * 16 + n;
      int c = cc >> 1, which = cc & 1;
      const float* W = which ? Ws : Wf;
      v = W[(size_t)k * HID + c];
    } else {
      int g = (tc - 16) >> 1, which = (tc - 16) & 1;
      int c = g * 16 + n;
      const float* W = which ? Ws : Wf;
      v = W[(size_t)(128 + k) * HID + c];
    }
    WnB[i] = (unsigned short)f2bf(v);
    if (i < 256) {
      int c2 = i >> 1, w2 = i & 1;
      biasv[i] = w2 ? bs[c2] : bf[c2];
    }
  }
}

// ---------------- CSR build: histogram -> scan -> scatter(+eattr pack) ----------------
__global__ void deg_hist(const int* __restrict__ dst, int* __restrict__ deg) {
  int e = blockIdx.x * blockDim.x + threadIdx.x;
  if (e < NEDGES) atomicAdd(&deg[dst[e]], 1);
}

__global__ __launch_bounds__(256) void scan_block(const int* __restrict__ deg, int* __restrict__ bsum) {
  __shared__ int s[256];
  int i = blockIdx.x * 256 + threadIdx.x;
  s[threadIdx.x] = (i < NNODES) ? deg[i] : 0;
  __syncthreads();
  for (int off = 128; off > 0; off >>= 1) {
    if (threadIdx.x < off) s[threadIdx.x] += s[threadIdx.x + off];
    __syncthreads();
  }
  if (threadIdx.x == 0) bsum[blockIdx.x] = s[0];
}

__global__ __launch_bounds__(256) void scan_top(const int* __restrict__ bsum,
                                                int* __restrict__ bpre) {
  __shared__ int s[256];
  int t = threadIdx.x;
  int v = (t < NB_SCAN) ? bsum[t] : 0;
  s[t] = v;
  __syncthreads();
  for (int off = 1; off < 256; off <<= 1) {
    int u = (t >= off) ? s[t - off] : 0;
    __syncthreads();
    s[t] += u;
    __syncthreads();
  }
  if (t < NB_SCAN) bpre[t] = s[t] - v;
}

__global__ __launch_bounds__(256) void scan_final(const int* __restrict__ deg,
                                                  const int* __restrict__ bpre,
                                                  int* __restrict__ cursor) {
  __shared__ int s[256];
  int i = blockIdx.x * 256 + threadIdx.x;
  int v = (i < NNODES) ? deg[i] : 0;
  s[threadIdx.x] = v;
  __syncthreads();
  for (int off = 1; off < 256; off <<= 1) {
    int t = (threadIdx.x >= off) ? s[threadIdx.x - off] : 0;
    __syncthreads();
    s[threadIdx.x] += t;
    __syncthreads();
  }
  if (i < NNODES) cursor[i] = bpre[blockIdx.x] + s[threadIdx.x] - v;  // exclusive
}

// scatter + fused eattr->bf16 pack in sorted order
__global__ void scatter_edges_pack(const int* __restrict__ src, const int* __restrict__ dst,
                                   const float* __restrict__ eattr, int* __restrict__ cursor,
                                   int2* __restrict__ se2, unsigned short* __restrict__ eaB) {
  int e = blockIdx.x * blockDim.x + threadIdx.x;
  if (e >= NEDGES) return;
  int d = dst[e];
  int pos = atomicAdd(&cursor[d], 1);
  se2[pos] = make_int2(src[e], d);
  const float* ep = eattr + (size_t)e * NRBF;
  unsigned short* op = eaB + (size_t)pos * NRBF;
#pragma unroll
  for (int part = 0; part < 4; ++part) {
    const float4 v0 = *(const float4*)&ep[part * 8];
    const float4 v1 = *(const float4*)&ep[part * 8 + 4];
    short8 o;
    o[0] = f2bf(v0.x); o[1] = f2bf(v0.y); o[2] = f2bf(v0.z); o[3] = f2bf(v0.w);
    o[4] = f2bf(v1.x); o[5] = f2bf(v1.y); o[6] = f2bf(v1.z); o[7] = f2bf(v1.w);
    *(short8*)&op[part * 8] = o;
  }
}

// ---------------- node MFMA GEMM, fused embed (mode 0) / relu-add+agg-zero (mode 1) ---
// Pdst[n][256] fp32 interleaved {f,s}; Psrc[n][128] uint packed fp16 {f,s}.
// mode 1 also ZEROES agg rows after consuming them (kills 2 of 3 agg memsets).
__global__ __launch_bounds__(256) void node_mfma(
    const int* __restrict__ x, const float* __restrict__ emb,
    float* __restrict__ h, float* __restrict__ agg,
    const unsigned short* __restrict__ WnB, const float* __restrict__ biasv,
    float* __restrict__ Pdst, unsigned int* __restrict__ Psrc, int mode, int N) {
  const int tid = threadIdx.x;
  const int wv = tid >> 6;
  const int lane = tid & 63;
  const int q = lane >> 4;
  const int n = lane & 15;
  const int nb = blockIdx.x * 32 + (wv >> 1) * 16;
  const int srcwave = wv & 1;
  const int ctile0 = srcwave * 16;

  const bool valid = (nb + n) < N;
  int anode = nb + n;
  if (anode >= N) anode = N - 1;
  float* hp = h + (size_t)anode * HID;

  short8 a[4];
  if (mode == 0) {
    const float* ep = emb + (size_t)x[anode] * HID;
#pragma unroll
    for (int kt = 0; kt < 4; ++kt) {
      const float4 e0 = *(const float4*)&ep[kt * 32 + q * 8];
      const float4 e1 = *(const float4*)&ep[kt * 32 + q * 8 + 4];
      if (valid && !srcwave) {
        *(float4*)&hp[kt * 32 + q * 8] = e0;
        *(float4*)&hp[kt * 32 + q * 8 + 4] = e1;
      }
      a[kt][0] = f2bf(e0.x); a[kt][1] = f2bf(e0.y);
      a[kt][2] = f2bf(e0.z); a[kt][3] = f2bf(e0.w);
      a[kt][4] = f2bf(e1.x); a[kt][5] = f2bf(e1.y);
      a[kt][6] = f2bf(e1.z); a[kt][7] = f2bf(e1.w);
    }
  } else {
    float* ap = agg + (size_t)anode * HID;
    float4 ev[8];
#pragma unroll
    for (int kt = 0; kt < 4; ++kt) {
      float4 e0 = *(const float4*)&hp[kt * 32 + q * 8];
      float4 e1 = *(const float4*)&hp[kt * 32 + q * 8 + 4];
      const float4 g0 = *(const float4*)&ap[kt * 32 + q * 8];
      const float4 g1 = *(const float4*)&ap[kt * 32 + q * 8 + 4];
      e0.x = fmaxf(e0.x + g0.x, 0.f); e0.y = fmaxf(e0.y + g0.y, 0.f);
      e0.z = fmaxf(e0.z + g0.z, 0.f); e0.w = fmaxf(e0.w + g0.w, 0.f);
      e1.x = fmaxf(e1.x + g1.x, 0.f); e1.y = fmaxf(e1.y + g1.y, 0.f);
      e1.z = fmaxf(e1.z + g1.z, 0.f); e1.w = fmaxf(e1.w + g1.w, 0.f);
      ev[2 * kt] = e0;
      ev[2 * kt + 1] = e1;
      a[kt][0] = f2bf(e0.x); a[kt][1] = f2bf(e0.y);
      a[kt][2] = f2bf(e0.z); a[kt][3] = f2bf(e0.w);
      a[kt][4] = f2bf(e1.x); a[kt][5] = f2bf(e1.y);
      a[kt][6] = f2bf(e1.z); a[kt][7] = f2bf(e1.w);
    }
    __syncthreads();  // all h/agg reads done before in-place writes (race fix R11)
    if (valid && !srcwave) {
      const float4 z4 = {0.f, 0.f, 0.f, 0.f};
#pragma unroll
      for (int kt = 0; kt < 4; ++kt) {
        *(float4*)&hp[kt * 32 + q * 8] = ev[2 * kt];
        *(float4*)&hp[kt * 32 + q * 8 + 4] = ev[2 * kt + 1];
        *(float4*)&ap[kt * 32 + q * 8] = z4;       // re-zero agg for next layer
        *(float4*)&ap[kt * 32 + q * 8 + 4] = z4;
      }
    }
  }

  const short8* WnB8 = (const short8*)WnB;
  f32x4 acc[16];
#pragma unroll
  for (int tc = 0; tc < 16; ++tc) acc[tc] = (f32x4){0.f, 0.f, 0.f, 0.f};

#pragma unroll
  for (int tc = 0; tc < 16; ++tc) {
#pragma unroll
    for (int kt = 0; kt < 4; ++kt) {
      short8 b = WnB8[((size_t)((ctile0 + tc) * 4 + kt)) * 64 + lane];
      acc[tc] = __builtin_amdgcn_mfma_f32_16x16x32_bf16(a[kt], b, acc[tc], 0, 0, 0);
    }
  }

  if (!srcwave) {
#pragma unroll
    for (int tc = 0; tc < 16; ++tc) {
      const int cout = tc * 16 + n;
      const float bv = biasv[cout];
#pragma unroll
      for (int r = 0; r < 4; ++r) {
        int nd = nb + q * 4 + r;
        if (nd < N) Pdst[(size_t)nd * 256 + cout] = acc[tc][r] + bv;
      }
    }
  } else {
#pragma unroll
    for (int g2 = 0; g2 < 8; ++g2) {
      const int c = g2 * 16 + n;
#pragma unroll
      for (int r = 0; r < 4; ++r) {
        int nd = nb + q * 4 + r;
        if (nd < N) Psrc[(size_t)nd * 128 + c] = packh2(acc[2 * g2][r], acc[2 * g2 + 1][r]);
      }
    }
  }
}

// ---------------- MFMA edge kernel, 3-phase, EPB=32 / 128 threads ----------------
// Phase 3 is SOFTWARE-PIPELINED: Psrc gather + fsL read for j+1 issued before
// computing j -- overlaps the ~300cyc loop-carried gather chain with compute.
__global__ __launch_bounds__(128) void edge_mfma(
    const float* __restrict__ Pdst, const unsigned int* __restrict__ Psrc,
    const unsigned short* __restrict__ eaB, const unsigned short* __restrict__ WtB,
    const int2* __restrict__ se2, float* __restrict__ agg) {
  __shared__ unsigned int fsL[EPB * SROW];
  __shared__ int srcL[EPB];
  __shared__ int dstL[EPB];
  __shared__ int grpStart[EPB + 1];
  __shared__ int sndS;

  const int tid = threadIdx.x;
  const int base = blockIdx.x * EPB;
  const int lane = tid & 63;

  // ---- Phase 1: wave-0 ballot-scan of sorted dsts -> groups ----
  if (tid < EPB) {
    int2 sd = se2[base + tid];
    srcL[tid] = sd.x;
    dstL[tid] = sd.y;
    int d = sd.y;
    int dprev = __shfl_up(d, 1);
    int flag = (tid == 0 || dprev != d) ? 1 : 0;
    unsigned long long mask = __ballot(flag);
    int slot = __popcll(mask & ((1ull << (lane + 1)) - 1)) - 1;
    if (flag) grpStart[slot] = tid;
    if (tid == 0) {
      int nd = __popcll(mask);
      sndS = nd;
      grpStart[nd] = EPB;
    }
  }

  // ---- Phase 2: MFMA (A-frags from pre-packed sorted bf16 eattr, coalesced) ----
  const int wv = tid >> 6;        // 0..1
  const int q = lane >> 4;
  const int n = lane & 15;

  const short8 afrag = *(const short8*)&eaB[(size_t)(base + wv * 16 + n) * 32 + q * 8];

  const short8* WtB8 = (const short8*)WtB;
  const f32x4 zero4 = {0.f, 0.f, 0.f, 0.f};
  const int rowb = wv * 16 + q * 4;

#pragma unroll
  for (int t = 0; t < 8; ++t) {
    short8 bfr = WtB8[t * 64 + lane];
    short8 bsr = WtB8[(8 + t) * 64 + lane];
    f32x4 cf = __builtin_amdgcn_mfma_f32_16x16x32_bf16(afrag, bfr, zero4, 0, 0, 0);
    f32x4 cs = __builtin_amdgcn_mfma_f32_16x16x32_bf16(afrag, bsr, zero4, 0, 0, 0);
#pragma unroll
    for (int r = 0; r < 4; ++r) {
      fsL[(rowb + r) * SROW + t * 16 + n] = packbf2(cf[r], cs[r]);
    }
  }
  __syncthreads();

  // ---- Phase 3: per-group accumulation, pipelined, 2 wave-teams, 2 ch/lane ----
  const int nd = sndS;
  for (int g = wv; g < nd; g += 2) {
    const int jb = grpStart[g];
    const int je = grpStart[g + 1];
    const int d = __builtin_amdgcn_readfirstlane(dstL[jb]);
    const float4 pd = *(const float4*)&Pdst[(size_t)d * 256 + 4 * lane];  // {f0,s0,f1,s1}
    float acc0 = 0.f, acc1 = 0.f;

    // prologue: prefetch j = jb
    int s_nx = __builtin_amdgcn_readfirstlane(srcL[jb]);
    uint2 psp_nx = *(const uint2*)&Psrc[(size_t)s_nx * 128 + 2 * lane];
    uint2 pk_nx = *(const uint2*)&fsL[jb * SROW + 2 * lane];

    for (int j = jb; j < je; ++j) {
      const uint2 psp = psp_nx;
      const uint2 pk = pk_nx;
      // prefetch j+1 (clamped, branchless) before consuming j
      int jn = (j + 1 < je) ? (j + 1) : j;
      int s2 = __builtin_amdgcn_readfirstlane(srcL[jn]);
      psp_nx = *(const uint2*)&Psrc[(size_t)s2 * 128 + 2 * lane];
      pk_nx = *(const uint2*)&fsL[jn * SROW + 2 * lane];

      const float2 ps0 = __half22float2(*reinterpret_cast<const __half2*>(&psp.x));
      const float2 ps1 = __half22float2(*reinterpret_cast<const __half2*>(&psp.y));
      const float af0 = __uint_as_float(pk.x << 16);
      const float as0 = __uint_as_float(pk.x & 0xffff0000u);
      const float af1 = __uint_as_float(pk.y << 16);
      const float as1 = __uint_as_float(pk.y & 0xffff0000u);
      float zf0 = pd.x + ps0.x + af0;
      float zs0 = pd.y + ps0.y + as0;
      float zf1 = pd.z + ps1.x + af1;
      float zs1 = pd.w + ps1.y + as1;
      float sig0 = __builtin_amdgcn_rcpf(1.f + __expf(-zf0));
      float sig1 = __builtin_amdgcn_rcpf(1.f + __expf(-zf1));
      float sp0 = fmaxf(zs0, 0.f) + __logf(1.f + __expf(-fabsf(zs0)));
      float sp1 = fmaxf(zs1, 0.f) + __logf(1.f + __expf(-fabsf(zs1)));
      acc0 = fmaf(sig0, sp0, acc0);
      acc1 = fmaf(sig1, sp1, acc1);
    }
    float* ap = agg + (size_t)d * HID + 2 * lane;
    if (g == 0 || g == nd - 1) {
      atomicAdd(ap, acc0);
      atomicAdd(ap + 1, acc1);
    } else {
      *(float2*)ap = make_float2(acc0, acc1);
    }
  }
}

// ---------------- pooling: batch is SORTED -> run-detection, few atomics ----------------
__global__ __launch_bounds__(256) void pool_kernel(
    const float* __restrict__ h, const float* __restrict__ agg,
    const int* __restrict__ batch, float* __restrict__ sums, float* __restrict__ counts) {
  __shared__ int gidL[64];
  __shared__ int grpS[65];
  __shared__ int sndP;

  const int tid = threadIdx.x;
  const int lane = tid & 63;
  const int wv = tid >> 6;
  const int nb = blockIdx.x * 64;
  int nvalid = NNODES - nb;
  if (nvalid > 64) nvalid = 64;

  if (tid < 64) {
    int node = nb + tid;
    int g = batch[node < NNODES ? node : NNODES - 1];
    gidL[tid] = g;
    int gprev = __shfl_up(g, 1);
    int flag = (tid < nvalid && (tid == 0 || gprev != g)) ? 1 : 0;
    unsigned long long mask = __ballot(flag);
    int slot = __popcll(mask & ((lane == 63) ? ~0ull : ((1ull << (lane + 1)) - 1))) - 1;
    if (flag) grpS[slot] = tid;
    if (tid == 0) {
      int nd = __popcll(mask);
      sndP = nd;
      grpS[nd] = nvalid;
    }
  }
  __syncthreads();

  const int nd = sndP;
  for (int g = wv; g < nd; g += 4) {
    const int jb = grpS[g];
    const int je = grpS[g + 1];
    const int gid = __builtin_amdgcn_readfirstlane(gidL[jb]);
    float a0 = 0.f, a1 = 0.f;
    for (int j = jb; j < je; ++j) {
      const float2 hv = *(const float2*)&h[(size_t)(nb + j) * HID + 2 * lane];
      const float2 av = *(const float2*)&agg[(size_t)(nb + j) * HID + 2 * lane];
      a0 += fmaxf(hv.x + av.x, 0.f);
      a1 += fmaxf(hv.y + av.y, 0.f);
    }
    float* sp = sums + (size_t)gid * HID + 2 * lane;
    const bool bnd = (g == 0 || g == nd - 1);
    if (bnd) {
      atomicAdd(sp, a0);
      atomicAdd(sp + 1, a1);
    } else {
      *(float2*)sp = make_float2(a0, a1);
    }
    if (lane == 0) {
      if (bnd) atomicAdd(&counts[gid], (float)(je - jb));
      else counts[gid] = (float)(je - jb);
    }
  }
}

// ---------------- out[g] = (sums[g]/max(cnt,1)) @ Wlin + blin ----------------
__global__ __launch_bounds__(128) void final_kernel(
    const float* __restrict__ sums, const float* __restrict__ counts,
    const float* __restrict__ Wlin, const float* __restrict__ blin,
    float* __restrict__ out) {
  int g = blockIdx.x;
  int c = threadIdx.x;
  __shared__ float pool[HID];
  float cnt = counts[g];
  cnt = cnt > 1.f ? cnt : 1.f;
  pool[c] = sums[(size_t)g * HID + c] / cnt;
  __syncthreads();
  float acc = blin[c];
#pragma unroll 8
  for (int k = 0; k < HID; ++k) acc = fmaf(pool[k], Wlin[k * HID + c], acc);
  out[(size_t)g * HID + c] = acc;
}

extern "C" void kernel_launch(void* const* d_in, const int* in_sizes, int n_in,
                              void* d_out, int out_size, void* d_ws, size_t ws_size,
                              hipStream_t stream) {
  const int* x = (const int*)d_in[0];
  const int* eidx = (const int*)d_in[1];
  const float* eattr = (const float*)d_in[2];
  const int* batch = (const int*)d_in[3];
  const float* emb = (const float*)d_in[4];
  const float* Wf[3] = {(const float*)d_in[5], (const float*)d_in[9], (const float*)d_in[13]};
  const float* bf[3] = {(const float*)d_in[6], (const float*)d_in[10], (const float*)d_in[14]};
  const float* Ws[3] = {(const float*)d_in[7], (const float*)d_in[11], (const float*)d_in[15]};
  const float* bs[3] = {(const float*)d_in[8], (const float*)d_in[12], (const float*)d_in[16]};
  const float* Wlin = (const float*)d_in[17];
  const float* blin = (const float*)d_in[18];
  const int* srcp = eidx;
  const int* dstp = eidx + NEDGES;

  float* wsf = (float*)d_ws;
  float* h = wsf;                                    // N*128
  float* Pdst = h + (size_t)NNODES * HID;            // N*256 fp32 interleaved
  float* agg = Pdst + (size_t)NNODES * 256;          // N*128
  float* sums = agg + (size_t)NNODES * HID;          // 500*128
  float* counts = sums + (size_t)NGRAPH * HID;       // 500
  float* biasv3 = counts + NGRAPH;                   // 3*256
  unsigned int* Psrc = (unsigned int*)(biasv3 + 768);  // N*128 uint packed fp16
  unsigned short* WtB3 = (unsigned short*)(Psrc + (size_t)NNODES * 128);  // 3*8192
  unsigned short* WnB3 = WtB3 + 3 * 8192;            // 3*65536
  unsigned short* eaB = WnB3 + 3 * 65536;            // NEDGES*32 bf16
  int2* se2 = (int2*)(eaB + (size_t)NEDGES * 32);    // 800000 int2
  int* deg = (int*)(se2 + NEDGES);                   // 50000
  int* cursor = deg + NNODES;                        // 50000
  int* bsum = cursor + NNODES;                       // 196
  int* bpre = bsum + NB_SCAN;                        // 196

  // --- weight prep (all 3 layers, one launch) ---
  dim3 pgrid(288, 3);
  prep_all<<<pgrid, 256, 0, stream>>>(Wf[0], Ws[0], bf[0], bs[0],
                                      Wf[1], Ws[1], bf[1], bs[1],
                                      Wf[2], Ws[2], bf[2], bs[2],
                                      WtB3, WnB3, biasv3);

  // --- CSR build (edges layer-invariant: once per call) ---
  hipMemsetAsync(deg, 0, NNODES * sizeof(int), stream);
  deg_hist<<<(NEDGES + 255) / 256, 256, 0, stream>>>(dstp, deg);
  scan_block<<<NB_SCAN, 256, 0, stream>>>(deg, bsum);
  scan_top<<<1, 256, 0, stream>>>(bsum, bpre);
  scan_final<<<NB_SCAN, 256, 0, stream>>>(deg, bpre, cursor);
  scatter_edges_pack<<<(NEDGES + 255) / 256, 256, 0, stream>>>(srcp, dstp, eattr, cursor,
                                                               se2, eaB);

  // single agg zero: layer>=1 re-zeroed inside node_mfma mode 1
  hipMemsetAsync(agg, 0, (size_t)NNODES * HID * sizeof(float), stream);

  const int nblk_node = (NNODES + 31) / 32;  // 1563
  for (int l = 0; l < 3; ++l) {
    node_mfma<<<nblk_node, 256, 0, stream>>>(x, emb, h, agg, WnB3 + l * 65536,
                                             biasv3 + l * 256, Pdst, Psrc,
                                             l > 0 ? 1 : 0, NNODES);
    edge_mfma<<<NEBLK, 128, 0, stream>>>(Pdst, Psrc, eaB, WtB3 + l * 8192, se2, agg);
  }

  hipMemsetAsync(sums, 0, (size_t)(NGRAPH * HID + NGRAPH) * sizeof(float), stream);
  pool_kernel<<<(NNODES + 63) / 64, 256, 0, stream>>>(h, agg, batch, sums, counts);
  final_kernel<<<NGRAPH, 128, 0, stream>>>(sums, counts, Wlin, blin, (float*)d_out);
}